// Round 10
// baseline (149.806 us; speedup 1.0000x reference)
//
#include <hip/hip_runtime.h>

// Problem constants: B=2, S=2048, E=1024, H=16, D=64, WIN=16
#define BB 2
#define SS 2048
#define EE 1024
#define HH 16
#define DD 64
#define NY 5120   // merged projection output cols: [Kcls|Vcls|Qloc|Kloc|Vloc]

typedef __attribute__((ext_vector_type(8))) short short8;
typedef __attribute__((ext_vector_type(4))) float f32x4;

__device__ __forceinline__ float bf2f(unsigned short u) {
  union { unsigned int i; float f; } v; v.i = ((unsigned int)u) << 16; return v.f;
}
__device__ __forceinline__ unsigned short f2bf(float f) {
  unsigned int u = __float_as_uint(f);
  u += 0x7fff + ((u >> 16) & 1);   // RNE
  return (unsigned short)(u >> 16);
}
__device__ __forceinline__ void gload_lds16(const void* g, void* l) {
  __builtin_amdgcn_global_load_lds(
      (const __attribute__((address_space(1))) void*)g,
      (__attribute__((address_space(3))) void*)l, 16, 0, 0);
}

// ---------------- fused f32->bf16 casts + q_cls GEMV (one launch) ----------------
__global__ void cast_all(const float* __restrict__ s0, unsigned short* __restrict__ d0,
                         const float* __restrict__ s1, unsigned short* __restrict__ d1,
                         const float* __restrict__ s2, unsigned short* __restrict__ d2,
                         const float* __restrict__ s3, unsigned short* __restrict__ d3,
                         const float* __restrict__ in_w_cls,
                         const float* __restrict__ in_b_cls,
                         float* __restrict__ qcls) {
  int b = blockIdx.x;
  if (b >= 10240) {   // q_cls GEMV: 512 blocks x 4 rows
    int gw = (b - 10240) * 4 + (threadIdx.x >> 6);
    int lane = threadIdx.x & 63;
    int bb = gw >> 10, n = gw & 1023;
    const float* x = s0 + (size_t)bb * SS * EE;
    const float* w = in_w_cls + (size_t)n * EE;
    float s = 0.0f;
    for (int k = lane; k < EE; k += 64) s += x[k] * w[k];
    for (int o = 32; o; o >>= 1) s += __shfl_xor(s, o);
    if (lane == 0) qcls[bb * EE + n] = s + in_b_cls[n];
    return;
  }
  const float* s; unsigned short* d; int idx;
  if (b < 4096)      { s = s0; d = d0; idx = b; }
  else if (b < 6144) { s = s1; d = d1; idx = b - 4096; }
  else if (b < 9216) { s = s2; d = d2; idx = b - 6144; }
  else               { s = s3; d = d3; idx = b - 9216; }
  int i = (idx * 256 + threadIdx.x) * 4;
  float4 v = *reinterpret_cast<const float4*>(s + i);
  ushort4 o;
  o.x = f2bf(v.x); o.y = f2bf(v.y); o.z = f2bf(v.z); o.w = f2bf(v.w);
  *reinterpret_cast<ushort4*>(d + i) = o;
}

// ================= 256x320 projection GEMM — frag-pipelined 4-phase ==============
// Y[4096][5120] = Xbf[4096][1024] @ W[5120][1024]^T + bias
// 512 thr = 8 waves (2M x 4N), per-wave 128x80 (acc 8x5), BK=64, 16 K-tiles.
// FRAGMENT SOFTWARE PIPELINE (the m201 element previous rounds missed):
//   each phase issues the NEXT phase's ds_reads, then a COUNTED lgkmcnt that
//   waits only the frags it is about to consume (issued one phase earlier, so
//   their LDS latency hid under the previous MFMA cluster + barrier).
//   P0: rd P1-A(4)   lgkm(4)  MFMA20(kh0,mh0)   | stage B0-4(t+1)
//   P1: rd P2-B+A(9) lgkm(9)  MFMA20(kh0,mh1)   | stage A0-3(t+1)
//   P2: rd P3-A(4)   lgkm(4)  MFMA20(kh1,mh0)
//   P3:              lgkm(0)  MFMA20(kh1,mh1)   | vmcnt(0) seam (2-3 phases cover)
//   post-seam: rd next-tile P0 frags (9) — latency covered into next P0.
// One barrier per phase; intra-tile is hazard-free (reads buf c, stages c^1).
#define SBAR __builtin_amdgcn_sched_barrier(0)
#define RAWBAR do { SBAR; __builtin_amdgcn_s_barrier(); SBAR; } while (0)
#define WAITVM0 do { asm volatile("s_waitcnt vmcnt(0)" ::: "memory"); SBAR; } while (0)
#define LGKMW(n) do { asm volatile("s_waitcnt lgkmcnt(" #n ")" ::: "memory"); SBAR; } while (0)

__global__ __launch_bounds__(512, 2)
void gemm8p(const unsigned short* __restrict__ Ag,   // [4096][1024]
            const unsigned short* __restrict__ Bg,   // [5120][1024]
            const float* __restrict__ bcls,
            const float* __restrict__ bloc,
            unsigned short* __restrict__ Yout) {     // [4096][5120]
  __shared__ unsigned short As2[2][256][64];   // 64 KiB
  __shared__ unsigned short Bs2[2][320][64];   // 80 KiB
  char* ldsA = (char*)As2;
  char* ldsB = (char*)Bs2;

  const int tid = threadIdx.x;
  const int wid = tid >> 6;
  const int lane = tid & 63;
  const int wm = wid >> 2;     // 0..1 -> 128-row slice
  const int wn = wid & 3;      // 0..3 -> 80-col slice
  const int rl = lane & 15;
  const int g4 = lane >> 4;

  int bid = blockIdx.x;
  bid = (bid & 7) * 32 + (bid >> 3);     // XCD swizzle, bijective (256 = 8*32)
  const int tileM = (bid & 15) * 256;
  const int tileN = (bid >> 4) * 320;

  f32x4 acc[8][5] = {};
  short8 FA0[4], FA1[4], FB0[5], FB1[5];   // double-buffered fragments

  auto SA = [&](int c, int kk, int i) {
    int flat = i * 8192 + tid * 16;
    int row = flat >> 7;
    int colb = (flat & 127) ^ ((row & 7) << 4);
    gload_lds16(Ag + (size_t)(tileM + row) * 1024 + kk + (colb >> 1),
                ldsA + c * 32768 + i * 8192 + wid * 1024);
  };
  auto SB = [&](int c, int kk, int j) {
    int flat = j * 8192 + tid * 16;
    int row = flat >> 7;
    int colb = (flat & 127) ^ ((row & 7) << 4);
    gload_lds16(Bg + (size_t)(tileN + row) * 1024 + kk + (colb >> 1),
                ldsB + c * 40960 + j * 8192 + wid * 1024);
  };
  auto RD_A = [&](int c, int mh, int kh, short8* dst) {
#pragma unroll
    for (int m = 0; m < 4; ++m) {
      int row = wm * 128 + mh * 64 + m * 16 + rl;
      const char* base = ldsA + c * 32768 + row * 128;
      dst[m] = *(const short8*)(base + ((kh * 64 + g4 * 16) ^ ((row & 7) << 4)));
    }
  };
  auto RD_B = [&](int c, int kh, short8* dst) {
#pragma unroll
    for (int n = 0; n < 5; ++n) {
      int row = wn * 80 + n * 16 + rl;
      const char* base = ldsB + c * 40960 + row * 128;
      dst[n] = *(const short8*)(base + ((kh * 64 + g4 * 16) ^ ((row & 7) << 4)));
    }
  };
  auto MF20 = [&](short8* FB, short8* FA, int mh) {
    __builtin_amdgcn_s_setprio(1);
#pragma unroll
    for (int m = 0; m < 4; ++m)
#pragma unroll
      for (int n = 0; n < 5; ++n)
        acc[mh * 4 + m][n] = __builtin_amdgcn_mfma_f32_16x16x32_bf16(
            FB[n], FA[m], acc[mh * 4 + m][n], 0, 0, 0);
    __builtin_amdgcn_s_setprio(0);
  };

  // prologue: stage tile 0 -> buf0, then read P0 frags
  SB(0, 0, 0); SB(0, 0, 1); SB(0, 0, 2); SB(0, 0, 3); SB(0, 0, 4);
  SA(0, 0, 0); SA(0, 0, 1); SA(0, 0, 2); SA(0, 0, 3);
  WAITVM0;
  RAWBAR;
  RD_B(0, 0, FB0); RD_A(0, 0, 0, FA0);   // 9 reads: tile0 P0 frags

#pragma unroll 1
  for (int t = 0; t < 16; ++t) {
    const int c = t & 1;
    const int kk = (t + 1) * 64;
    const bool st = (t < 15);
    // P0 (kh0, mh0)
    RD_A(c, 1, 0, FA1);                                 // 4 reads for P1
    if (st) { SB(c ^ 1, kk, 0); SB(c ^ 1, kk, 1); SB(c ^ 1, kk, 2); SB(c ^ 1, kk, 3); SB(c ^ 1, kk, 4); }
    LGKMW(4);                                           // wait P0's 9, leave FA1's 4
    MF20(FB0, FA0, 0);
    RAWBAR;
    // P1 (kh0, mh1)
    RD_B(c, 1, FB1); RD_A(c, 0, 1, FA0);                // 9 reads for P2
    if (st) { SA(c ^ 1, kk, 0); SA(c ^ 1, kk, 1); SA(c ^ 1, kk, 2); SA(c ^ 1, kk, 3); }
    LGKMW(9);                                           // wait FA1's 4, leave new 9
    MF20(FB0, FA1, 1);
    RAWBAR;
    // P2 (kh1, mh0)
    RD_A(c, 1, 1, FA1);                                 // 4 reads for P3
    LGKMW(4);                                           // wait P1's 9, leave new 4
    MF20(FB1, FA0, 0);
    RAWBAR;
    // P3 (kh1, mh1)
    LGKMW(0);                                           // wait FA1's 4
    MF20(FB1, FA1, 1);
    if (st) WAITVM0;                                    // seam: staging 2-3 phases old
    RAWBAR;
    // post-seam: issue next tile's P0 frags (buf c^1 now published)
    if (st) { RD_B(c ^ 1, 0, FB0); RD_A(c ^ 1, 0, 0, FA0); }
  }

  // epilogue (swapped layout): lane holds 4 consecutive cols ->
  // row = tileM + wm*128 + m*16 + rl ; col = tileN + wn*80 + n*16 + g4*4 + r
  float4 bv4[5];
#pragma unroll
  for (int n = 0; n < 5; ++n) {
    int gc = tileN + wn * 80 + n * 16 + g4 * 4;
    bv4[n] = *(const float4*)((gc < 2048) ? &bcls[1024 + gc] : &bloc[gc - 2048]);
  }
#pragma unroll
  for (int m = 0; m < 8; ++m) {
    int gr = tileM + wm * 128 + m * 16 + rl;
    unsigned short* yrow = Yout + (size_t)gr * NY + tileN + wn * 80 + g4 * 4;
#pragma unroll
    for (int n = 0; n < 5; ++n) {
      ushort4 o;
      o.x = f2bf(acc[m][n][0] + bv4[n].x);
      o.y = f2bf(acc[m][n][1] + bv4[n].y);
      o.z = f2bf(acc[m][n][2] + bv4[n].z);
      o.w = f2bf(acc[m][n][3] + bv4[n].w);
      *(ushort4*)(yrow + n * 16) = o;
    }
  }
}

// ---------------- 128x128 2-phase GEMM (out-proj only) ----------------
template <int OUT_BF16>
__global__ __launch_bounds__(256, 4)
void gemm_bt(const unsigned short* __restrict__ A,
             const unsigned short* __restrict__ B,
             const float* __restrict__ bias0,
             void* __restrict__ C, int M, int N, int K) {
  __shared__ unsigned short As[2][128 * 32];
  __shared__ unsigned short Bs[2][128 * 32];
  const int tid = threadIdx.x;
  const int wid = tid >> 6;
  const int lane = tid & 63;

  const int nx = gridDim.x;
  int bid = blockIdx.y * nx + blockIdx.x;
  const int nwg = nx * gridDim.y;
  if ((nwg & 7) == 0) { int c = nwg >> 3; bid = (bid & 7) * c + (bid >> 3); }
  const int tileM = (bid % nx) * 128;
  const int tileN = (bid / nx) * 128;

  const int wm = (wid >> 1) * 64;
  const int wn = (wid & 1) * 64;
  const int rl = lane & 15;
  const int kc = (lane >> 4) * 8;

  f32x4 acc[4][4] = {};

  const int srow = tid >> 2;
  const int scol = (tid & 3) * 8;
  const unsigned short* gA = A + (size_t)(tileM + srow) * K + scol;
  const unsigned short* gB = B + (size_t)(tileN + srow) * K + scol;
  char* lA = (char*)As + wid * 1024;
  char* lB = (char*)Bs + wid * 1024;

  auto STAGE = [&](int buf, int k0) {
    gload_lds16(gA + k0, lA + buf * 8192);
    gload_lds16(gA + (size_t)64 * K + k0, lA + buf * 8192 + 4096);
    gload_lds16(gB + k0, lB + buf * 8192);
    gload_lds16(gB + (size_t)64 * K + k0, lB + buf * 8192 + 4096);
  };
  auto COMPUTE = [&](int buf) {
    const unsigned short* as = As[buf];
    const unsigned short* bs = Bs[buf];
    short8 af[4], bfg[4];
#pragma unroll
    for (int mi = 0; mi < 4; ++mi)
      af[mi] = *reinterpret_cast<const short8*>(&as[(wm + mi * 16 + rl) * 32 + kc]);
#pragma unroll
    for (int ni = 0; ni < 4; ++ni)
      bfg[ni] = *reinterpret_cast<const short8*>(&bs[(wn + ni * 16 + rl) * 32 + kc]);
#pragma unroll
    for (int mi = 0; mi < 4; ++mi)
#pragma unroll
      for (int ni = 0; ni < 4; ++ni)
        acc[mi][ni] = __builtin_amdgcn_mfma_f32_16x16x32_bf16(
            af[mi], bfg[ni], acc[mi][ni], 0, 0, 0);
  };

  STAGE(0, 0);
  asm volatile("s_waitcnt vmcnt(0)" ::: "memory");
  __syncthreads();
  int cur = 0;
  for (int k0 = 32; k0 < K; k0 += 32) {
    STAGE(cur ^ 1, k0);
    COMPUTE(cur);
    asm volatile("s_waitcnt vmcnt(0)" ::: "memory");
    __syncthreads();
    cur ^= 1;
  }
  COMPUTE(cur);

  const int crow0 = (lane >> 4) * 4;
  const int ccol = lane & 15;
#pragma unroll
  for (int mi = 0; mi < 4; ++mi)
#pragma unroll
    for (int ni = 0; ni < 4; ++ni) {
      int gc = tileN + wn + ni * 16 + ccol;
      float bv = bias0[gc];
#pragma unroll
      for (int r = 0; r < 4; ++r) {
        int gr = tileM + wm + mi * 16 + crow0 + r;
        if (gr < M) {
          float v = acc[mi][ni][r] + bv;
          if (OUT_BF16)
            ((unsigned short*)C)[(size_t)gr * N + gc] = f2bf(v);
          else
            ((float*)C)[(size_t)gr * N + gc] = v;
        }
      }
    }
}

// ---------------- fused attention: local (x<16) + global partials (x>=16) ----------------
#define QBL 128
#define VT_PAD 168
#define P_PAD 72
__global__ __launch_bounds__(256, 2)
void attn_fused(const float* __restrict__ qcls,
                const unsigned short* __restrict__ Y,
                float* __restrict__ part,
                unsigned short* __restrict__ CTX) {
  const int h = blockIdx.y, b = blockIdx.z;
  const int tid = threadIdx.x, wid = tid >> 6, lane = tid & 63;

  __shared__ unsigned short Vt[64][VT_PAD];
  __shared__ unsigned short Pl[4][32][P_PAD];
  __shared__ float qf[64];
  __shared__ float ps[256];
  __shared__ float red[8];
  __shared__ float pacc[4][64];

  if (blockIdx.x >= 16) {
    const int kc = blockIdx.x - 16;
    if (tid < 64) qf[tid] = qcls[b * EE + h * DD + tid];
    __syncthreads();

    int s = kc * 256 + tid;
    const short8* k8 = (const short8*)(Y + (size_t)(b * SS + s) * NY + h * DD);
    float dot = 0.0f;
#pragma unroll
    for (int i = 0; i < 8; ++i) {
      short8 kv = k8[i];
#pragma unroll
      for (int e = 0; e < 8; ++e) dot += qf[i * 8 + e] * bf2f((unsigned short)kv[e]);
    }
    dot *= 0.125f;

    float mx = dot;
    for (int o = 32; o; o >>= 1) mx = fmaxf(mx, __shfl_xor(mx, o));
    if ((tid & 63) == 0) red[tid >> 6] = mx;
    __syncthreads();
    float M = fmaxf(fmaxf(red[0], red[1]), fmaxf(red[2], red[3]));

    float p = __expf(dot - M);
    ps[tid] = p;
    float l = p;
    for (int o = 32; o; o >>= 1) l += __shfl_xor(l, o);
    if ((tid & 63) == 0) red[4 + (tid >> 6)] = l;
    __syncthreads();
    float L = red[4] + red[5] + red[6] + red[7];

    int g = tid >> 6, d = tid & 63;
    float acc = 0.0f;
    for (int sl = g; sl < 256; sl += 4)
      acc += ps[sl] * bf2f(Y[(size_t)(b * SS + kc * 256 + sl) * NY + 1024 + h * DD + d]);
    pacc[g][d] = acc;
    __syncthreads();
    if (g == 0) {
      float a = pacc[0][d] + pacc[1][d] + pacc[2][d] + pacc[3][d];
      float* pp = part + ((size_t)(b * HH + h) * 8 + kc) * 66;
      if (d == 0) { pp[0] = M; pp[1] = L; }
      pp[2 + d] = a;
    }
    return;
  }

  // ===== local attention via MFMA =====
  const int s0 = blockIdx.x * QBL;
  const int rl = lane & 15, g = lane >> 4;

  for (int task = tid; task < 640; task += 256) {
    int kp = task % 80, ch = task / 80;
    int k0 = kp * 2;
    int kg0 = min(max(s0 - 16 + k0, 0), SS - 1);
    int kg1 = min(max(s0 - 16 + k0 + 1, 0), SS - 1);
    short8 a = *(const short8*)&Y[(size_t)(b * SS + kg0) * NY + 4096 + h * DD + ch * 8];
    short8 bv = *(const short8*)&Y[(size_t)(b * SS + kg1) * NY + 4096 + h * DD + ch * 8];
#pragma unroll
    for (int e = 0; e < 8; ++e) {
      unsigned int w = (unsigned int)(unsigned short)a[e] |
                       ((unsigned int)(unsigned short)bv[e] << 16);
      *(unsigned int*)&Vt[ch * 8 + e][k0] = w;
    }
  }
  __syncthreads();

  const int qb = s0 + wid * 32;
  const int kb = qb - 16;

  short8 ak[4][2];
#pragma unroll
  for (int kt = 0; kt < 4; ++kt) {
    int kg = min(max(kb + kt * 16 + rl, 0), SS - 1);
    const unsigned short* kr = &Y[(size_t)(b * SS + kg) * NY + 3072 + h * DD + g * 8];
#pragma unroll
    for (int ks = 0; ks < 2; ++ks) ak[kt][ks] = *(const short8*)(kr + ks * 32);
  }
  short8 bq[2][2];
#pragma unroll
  for (int cc = 0; cc < 2; ++cc) {
    const unsigned short* qr = &Y[(size_t)(b * SS + qb + cc * 16 + rl) * NY + 2048 + h * DD + g * 8];
#pragma unroll
    for (int ks = 0; ks < 2; ++ks) bq[cc][ks] = *(const short8*)(qr + ks * 32);
  }

  f32x4 accs[4][2] = {};
#pragma unroll
  for (int kt = 0; kt < 4; ++kt)
#pragma unroll
    for (int cc = 0; cc < 2; ++cc)
#pragma unroll
      for (int ks = 0; ks < 2; ++ks)
        accs[kt][cc] = __builtin_amdgcn_mfma_f32_16x16x32_bf16(
            ak[kt][ks], bq[cc][ks], accs[kt][cc], 0, 0, 0);

  float mrow[2] = {-3e38f, -3e38f};
#pragma unroll
  for (int kt = 0; kt < 4; ++kt)
#pragma unroll
    for (int cc = 0; cc < 2; ++cc)
#pragma unroll
      for (int r = 0; r < 4; ++r) {
        int kg = kb + kt * 16 + 4 * g + r;
        int qg = qb + cc * 16 + rl;
        bool valid = (kg >= qg - 16) && (kg <= qg + 16) && (kg >= 1) && (kg < SS);
        float v = valid ? accs[kt][cc][r] : -3e38f;
        accs[kt][cc][r] = v;
        mrow[cc] = fmaxf(mrow[cc], v);
      }
#pragma unroll
  for (int cc = 0; cc < 2; ++cc) {
    float m = mrow[cc];
    m = fmaxf(m, __shfl_xor(m, 16));
    m = fmaxf(m, __shfl_xor(m, 32));
    mrow[cc] = m;
  }

  float zrow[2] = {0.0f, 0.0f};
#pragma unroll
  for (int cc = 0; cc < 2; ++cc)
#pragma unroll
    for (int kt = 0; kt < 4; ++kt) {
      ushort4 pw;
#pragma unroll
      for (int r = 0; r < 4; ++r) {
        float p = __expf((accs[kt][cc][r] - mrow[cc]) * 0.125f);
        zrow[cc] += p;
        ((unsigned short*)&pw)[r] = f2bf(p);
      }
      *(ushort4*)&Pl[wid][cc * 16 + rl][kt * 16 + 4 * g] = pw;
    }
#pragma unroll
  for (int cc = 0; cc < 2; ++cc) {
    float z = zrow[cc];
    z += __shfl_xor(z, 16);
    z += __shfl_xor(z, 32);
    zrow[cc] = 1.0f / z;
  }

  f32x4 accp[4][2] = {};
#pragma unroll
  for (int ks = 0; ks < 2; ++ks) {
    short8 bp[2];
#pragma unroll
    for (int cc = 0; cc < 2; ++cc)
      bp[cc] = *(const short8*)&Pl[wid][cc * 16 + rl][ks * 32 + g * 8];
#pragma unroll
    for (int mt = 0; mt < 4; ++mt) {
      short8 av = *(const short8*)&Vt[mt * 16 + rl][wid * 32 + ks * 32 + g * 8];
#pragma unroll
      for (int cc = 0; cc < 2; ++cc)
        accp[mt][cc] = __builtin_amdgcn_mfma_f32_16x16x32_bf16(
            av, bp[cc], accp[mt][cc], 0, 0, 0);
    }
  }

#pragma unroll
  for (int mt = 0; mt < 4; ++mt)
#pragma unroll
    for (int cc = 0; cc < 2; ++cc) {
      int token = qb + cc * 16 + rl;
      if (token == 0) {
        *(ushort4*)&CTX[(size_t)(b * SS) * EE + h * DD + mt * 16 + 4 * g] = ushort4{0, 0, 0, 0};
        continue;
      }
      ushort4 o;
#pragma unroll
      for (int r = 0; r < 4; ++r)
        ((unsigned short*)&o)[r] = f2bf(accp[mt][cc][r] * zrow[cc]);
      *(ushort4*)&CTX[(size_t)(b * SS + token) * EE + h * DD + mt * 16 + 4 * g] = o;
    }
}

// ---------------- cls output rows: combine partials + GEMV (one launch) ----------------
__global__ void gemv_cls(const float* __restrict__ part,
                         const float* __restrict__ Wc,     // out_w_cls [1024][1024]
                         const float* __restrict__ bc,
                         float* __restrict__ out) {
  __shared__ float ctx[EE];
  __shared__ float u[HH][8];
  const int b = blockIdx.x >> 8;
  const int tid = threadIdx.x;
  const float* pb = part + (size_t)b * HH * 8 * 66;
  if (tid < HH) {
    const float* pp = pb + tid * 8 * 66;
    float M = -1e30f;
#pragma unroll
    for (int i = 0; i < 8; ++i) M = fmaxf(M, pp[i * 66]);
    float Z = 0.0f, w[8];
#pragma unroll
    for (int i = 0; i < 8; ++i) { w[i] = __expf(pp[i * 66] - M); Z += w[i] * pp[i * 66 + 1]; }
#pragma unroll
    for (int i = 0; i < 8; ++i) u[tid][i] = w[i] / Z;
  }
  __syncthreads();
  for (int k = tid; k < EE; k += 256) {
    int hh = k >> 6, d = k & 63;
    const float* pp = pb + hh * 8 * 66 + 2 + d;
    float a = 0.0f;
#pragma unroll
    for (int i = 0; i < 8; ++i) a += u[hh][i] * pp[i * 66];
    ctx[k] = a;
  }
  __syncthreads();
  int n = (blockIdx.x & 255) * 4 + (tid >> 6);
  int lane = tid & 63;
  const float* w = Wc + (size_t)n * EE;
  float s = 0.0f;
  for (int k = lane; k < EE; k += 64) s += ctx[k] * w[k];
  for (int o = 32; o; o >>= 1) s += __shfl_xor(s, o);
  if (lane == 0) out[(size_t)b * SS * EE + n] = s + bc[n];
}

extern "C" void kernel_launch(void* const* d_in, const int* in_sizes, int n_in,
                              void* d_out, int out_size, void* d_ws, size_t ws_size,
                              hipStream_t stream) {
  const float* hs        = (const float*)d_in[0];
  const float* in_w_cls  = (const float*)d_in[1];
  const float* in_b_cls  = (const float*)d_in[2];
  const float* out_w_cls = (const float*)d_in[3];
  const float* out_b_cls = (const float*)d_in[4];
  const float* in_w_loc  = (const float*)d_in[5];
  const float* in_b_loc  = (const float*)d_in[6];
  const float* out_w_loc = (const float*)d_in[7];
  const float* out_b_loc = (const float*)d_in[8];
  float* out = (float*)d_out;

  const int M = BB * SS;  // 4096
  char* ws = (char*)d_ws;
  size_t off = 0;
  auto alloc = [&](size_t bytes) { char* p = ws + off; off += (bytes + 255) & ~(size_t)255; return p; };
  unsigned short* Xbf  = (unsigned short*)alloc((size_t)M * EE * 2);
  unsigned short* W    = (unsigned short*)alloc((size_t)NY * EE * 2);
  unsigned short* Wout = (unsigned short*)alloc((size_t)EE * EE * 2);
  unsigned short* Yb   = (unsigned short*)alloc((size_t)M * NY * 2);
  unsigned short* CTX  = (unsigned short*)alloc((size_t)M * EE * 2);
  float* qcls = (float*)alloc(2 * EE * 4);
  float* part = (float*)alloc((size_t)BB * HH * 8 * 66 * 4);

  // 1) fused casts + q_cls GEMV
  cast_all<<<10752, 256, 0, stream>>>(
      hs, Xbf,
      in_w_cls + (size_t)EE * EE, W,
      in_w_loc, W + (size_t)2048 * EE,
      out_w_loc, Wout,
      in_w_cls, in_b_cls, qcls);

  // 2) merged projection GEMM (frag-pipelined 4-phase, 256x320, 256 blocks)
  gemm8p<<<256, 512, 0, stream>>>(Xbf, W, in_b_cls, in_b_loc, Yb);

  // 3) fused attention (local MFMA + cls partials)
  attn_fused<<<dim3(24, HH, BB), 256, 0, stream>>>(qcls, Yb, part, CTX);

  // 4) local output projection
  {
    dim3 g3(M / 128, EE / 128);
    gemm_bt<0><<<g3, 256, 0, stream>>>(CTX, Wout, out_b_loc, out, M, EE, EE);
  }

  // 5) cls output rows (combine + GEMV fused)
  gemv_cls<<<512, 256, 0, stream>>>(part, out_w_cls, out_b_cls, out);
}

// Round 14
// 127.668 us; speedup vs baseline: 1.1734x; 1.1734x over previous
//
#include <hip/hip_runtime.h>

// Problem constants: B=2, S=2048, E=1024, H=16, D=64, WIN=16
#define BB 2
#define SS 2048
#define EE 1024
#define HH 16
#define DD 64
#define NY 5120   // merged projection output cols: [Kcls|Vcls|Qloc|Kloc|Vloc]

typedef __attribute__((ext_vector_type(8))) short short8;
typedef __attribute__((ext_vector_type(4))) float f32x4;

__device__ __forceinline__ float bf2f(unsigned short u) {
  union { unsigned int i; float f; } v; v.i = ((unsigned int)u) << 16; return v.f;
}
__device__ __forceinline__ unsigned short f2bf(float f) {
  unsigned int u = __float_as_uint(f);
  u += 0x7fff + ((u >> 16) & 1);   // RNE
  return (unsigned short)(u >> 16);
}
__device__ __forceinline__ void gload_lds16(const void* g, void* l) {
  __builtin_amdgcn_global_load_lds(
      (const __attribute__((address_space(1))) void*)g,
      (__attribute__((address_space(3))) void*)l, 16, 0, 0);
}

// ---------------- fused f32->bf16 casts + q_cls GEMV (one launch) ----------------
__global__ void cast_all(const float* __restrict__ s0, unsigned short* __restrict__ d0,
                         const float* __restrict__ s1, unsigned short* __restrict__ d1,
                         const float* __restrict__ s2, unsigned short* __restrict__ d2,
                         const float* __restrict__ s3, unsigned short* __restrict__ d3,
                         const float* __restrict__ in_w_cls,
                         const float* __restrict__ in_b_cls,
                         float* __restrict__ qcls) {
  int b = blockIdx.x;
  if (b >= 10240) {   // q_cls GEMV: 512 blocks x 4 rows
    int gw = (b - 10240) * 4 + (threadIdx.x >> 6);
    int lane = threadIdx.x & 63;
    int bb = gw >> 10, n = gw & 1023;
    const float* x = s0 + (size_t)bb * SS * EE;
    const float* w = in_w_cls + (size_t)n * EE;
    float s = 0.0f;
    for (int k = lane; k < EE; k += 64) s += x[k] * w[k];
    for (int o = 32; o; o >>= 1) s += __shfl_xor(s, o);
    if (lane == 0) qcls[bb * EE + n] = s + in_b_cls[n];
    return;
  }
  const float* s; unsigned short* d; int idx;
  if (b < 4096)      { s = s0; d = d0; idx = b; }
  else if (b < 6144) { s = s1; d = d1; idx = b - 4096; }
  else if (b < 9216) { s = s2; d = d2; idx = b - 6144; }
  else               { s = s3; d = d3; idx = b - 9216; }
  int i = (idx * 256 + threadIdx.x) * 4;
  float4 v = *reinterpret_cast<const float4*>(s + i);
  ushort4 o;
  o.x = f2bf(v.x); o.y = f2bf(v.y); o.z = f2bf(v.z); o.w = f2bf(v.w);
  *reinterpret_cast<ushort4*>(d + i) = o;
}

// ================= 8-phase 256x320 projection GEMM (r6-proven 48.8us schedule) ====
// Y[4096][5120] = Xbf[4096][1024] @ W[5120][1024]^T + bias
// 512 thr = 8 waves (2M x 4N), per-wave 128x80 (acc 8x5), BK=64, 16 K-tiles.
// Staging of t+1 into buf c^1 (no WAR: reads hit buf c): A slabs at P0/P1,
// B slabs at P2/P3; seam vmcnt(0) at P3 end. Scalar epilogue, original operand order.
#define SBAR __builtin_amdgcn_sched_barrier(0)
#define RAWBAR do { SBAR; __builtin_amdgcn_s_barrier(); SBAR; } while (0)
#define WAITVM0 do { asm volatile("s_waitcnt vmcnt(0)" ::: "memory"); SBAR; } while (0)
#define LGKM0 do { asm volatile("s_waitcnt lgkmcnt(0)" ::: "memory"); SBAR; } while (0)

#define MFMA20(MH)                                                                   \
  _Pragma("unroll")                                                                  \
  for (int m = 0; m < 4; ++m)                                                        \
    _Pragma("unroll")                                                                \
    for (int n = 0; n < 5; ++n)                                                      \
      acc[(MH) * 4 + m][n] = __builtin_amdgcn_mfma_f32_16x16x32_bf16(                \
          afr[m], bfr[n], acc[(MH) * 4 + m][n], 0, 0, 0);

__global__ __launch_bounds__(512, 2)
void gemm8p(const unsigned short* __restrict__ Ag,   // [4096][1024]
            const unsigned short* __restrict__ Bg,   // [5120][1024]
            const float* __restrict__ bcls,
            const float* __restrict__ bloc,
            unsigned short* __restrict__ Yout) {     // [4096][5120]
  __shared__ unsigned short As2[2][256][64];   // 64 KiB
  __shared__ unsigned short Bs2[2][320][64];   // 80 KiB
  char* ldsA = (char*)As2;
  char* ldsB = (char*)Bs2;

  const int tid = threadIdx.x;
  const int wid = tid >> 6;
  const int lane = tid & 63;
  const int wm = wid >> 2;     // 0..1 -> 128-row slice
  const int wn = wid & 3;      // 0..3 -> 80-col slice
  const int rl = lane & 15;
  const int g4 = lane >> 4;

  int bid = blockIdx.x;
  bid = (bid & 7) * 32 + (bid >> 3);     // XCD swizzle, bijective (256 = 8*32)
  const int tileM = (bid & 15) * 256;
  const int tileN = (bid >> 4) * 320;

  f32x4 acc[8][5] = {};
  short8 afr[4], bfr[5];

  auto SA = [&](int c, int kk, int i) {
    int flat = i * 8192 + tid * 16;
    int row = flat >> 7;
    int colb = (flat & 127) ^ ((row & 7) << 4);
    gload_lds16(Ag + (size_t)(tileM + row) * 1024 + kk + (colb >> 1),
                ldsA + c * 32768 + i * 8192 + wid * 1024);
  };
  auto SB = [&](int c, int kk, int j) {
    int flat = j * 8192 + tid * 16;
    int row = flat >> 7;
    int colb = (flat & 127) ^ ((row & 7) << 4);
    gload_lds16(Bg + (size_t)(tileN + row) * 1024 + kk + (colb >> 1),
                ldsB + c * 40960 + j * 8192 + wid * 1024);
  };
  auto DSA = [&](int c, int mh, int kh) {
#pragma unroll
    for (int m = 0; m < 4; ++m) {
      int row = wm * 128 + mh * 64 + m * 16 + rl;
      const char* base = ldsA + c * 32768 + row * 128;
      afr[m] = *(const short8*)(base + ((kh * 64 + g4 * 16) ^ ((row & 7) << 4)));
    }
  };
  auto DSB = [&](int c, int kh) {
#pragma unroll
    for (int n = 0; n < 5; ++n) {
      int row = wn * 80 + n * 16 + rl;
      const char* base = ldsB + c * 40960 + row * 128;
      bfr[n] = *(const short8*)(base + ((kh * 64 + g4 * 16) ^ ((row & 7) << 4)));
    }
  };

  // prologue: tile 0 -> buf0
  SA(0, 0, 0); SA(0, 0, 1); SA(0, 0, 2); SA(0, 0, 3);
  SB(0, 0, 0); SB(0, 0, 1); SB(0, 0, 2); SB(0, 0, 3); SB(0, 0, 4);
  WAITVM0;
  RAWBAR;

#pragma unroll 1
  for (int t = 0; t < 16; ++t) {
    const int c = t & 1;
    const int kk = (t + 1) * 64;
    const bool st = (t < 15);
    // phase 0: (mh0, kh0)
    DSB(c, 0); DSA(c, 0, 0);
    if (st) { SA(c ^ 1, kk, 0); SA(c ^ 1, kk, 1); }
    RAWBAR; LGKM0;
    __builtin_amdgcn_s_setprio(1); MFMA20(0); __builtin_amdgcn_s_setprio(0);
    RAWBAR;
    // phase 1: (mh1, kh0)
    DSA(c, 1, 0);
    if (st) { SA(c ^ 1, kk, 2); SA(c ^ 1, kk, 3); }
    RAWBAR; LGKM0;
    __builtin_amdgcn_s_setprio(1); MFMA20(1); __builtin_amdgcn_s_setprio(0);
    RAWBAR;
    // phase 2: (mh0, kh1)
    DSB(c, 1); DSA(c, 0, 1);
    if (st) { SB(c ^ 1, kk, 0); SB(c ^ 1, kk, 1); SB(c ^ 1, kk, 2); }
    RAWBAR; LGKM0;
    __builtin_amdgcn_s_setprio(1); MFMA20(0); __builtin_amdgcn_s_setprio(0);
    RAWBAR;
    // phase 3: (mh1, kh1); seam drain
    DSA(c, 1, 1);
    if (st) { SB(c ^ 1, kk, 3); SB(c ^ 1, kk, 4); }
    RAWBAR; LGKM0;
    __builtin_amdgcn_s_setprio(1); MFMA20(1); __builtin_amdgcn_s_setprio(0);
    if (st) WAITVM0;
    RAWBAR;
  }

  // epilogue: C row = tileM + wm*128 + m*16 + g4*4 + r, col = tileN + wn*80 + n*16 + rl
#pragma unroll
  for (int m = 0; m < 8; ++m)
#pragma unroll
    for (int n = 0; n < 5; ++n) {
      int gc = tileN + wn * 80 + n * 16 + rl;
      float bv = (gc < 2048) ? bcls[1024 + gc] : bloc[gc - 2048];
#pragma unroll
      for (int r = 0; r < 4; ++r) {
        int gr = tileM + wm * 128 + m * 16 + g4 * 4 + r;
        Yout[(size_t)gr * NY + gc] = f2bf(acc[m][n][r] + bv);
      }
    }
}

// ---------------- 128x128 2-phase GEMM (out-proj only) ----------------
template <int OUT_BF16>
__global__ __launch_bounds__(256, 4)
void gemm_bt(const unsigned short* __restrict__ A,
             const unsigned short* __restrict__ B,
             const float* __restrict__ bias0,
             void* __restrict__ C, int M, int N, int K) {
  __shared__ unsigned short As[2][128 * 32];
  __shared__ unsigned short Bs[2][128 * 32];
  const int tid = threadIdx.x;
  const int wid = tid >> 6;
  const int lane = tid & 63;

  const int nx = gridDim.x;
  int bid = blockIdx.y * nx + blockIdx.x;
  const int nwg = nx * gridDim.y;
  if ((nwg & 7) == 0) { int c = nwg >> 3; bid = (bid & 7) * c + (bid >> 3); }
  const int tileM = (bid % nx) * 128;
  const int tileN = (bid / nx) * 128;

  const int wm = (wid >> 1) * 64;
  const int wn = (wid & 1) * 64;
  const int rl = lane & 15;
  const int kc = (lane >> 4) * 8;

  f32x4 acc[4][4] = {};

  const int srow = tid >> 2;
  const int scol = (tid & 3) * 8;
  const unsigned short* gA = A + (size_t)(tileM + srow) * K + scol;
  const unsigned short* gB = B + (size_t)(tileN + srow) * K + scol;
  char* lA = (char*)As + wid * 1024;
  char* lB = (char*)Bs + wid * 1024;

  auto STAGE = [&](int buf, int k0) {
    gload_lds16(gA + k0, lA + buf * 8192);
    gload_lds16(gA + (size_t)64 * K + k0, lA + buf * 8192 + 4096);
    gload_lds16(gB + k0, lB + buf * 8192);
    gload_lds16(gB + (size_t)64 * K + k0, lB + buf * 8192 + 4096);
  };
  auto COMPUTE = [&](int buf) {
    const unsigned short* as = As[buf];
    const unsigned short* bs = Bs[buf];
    short8 af[4], bfg[4];
#pragma unroll
    for (int mi = 0; mi < 4; ++mi)
      af[mi] = *reinterpret_cast<const short8*>(&as[(wm + mi * 16 + rl) * 32 + kc]);
#pragma unroll
    for (int ni = 0; ni < 4; ++ni)
      bfg[ni] = *reinterpret_cast<const short8*>(&bs[(wn + ni * 16 + rl) * 32 + kc]);
#pragma unroll
    for (int mi = 0; mi < 4; ++mi)
#pragma unroll
      for (int ni = 0; ni < 4; ++ni)
        acc[mi][ni] = __builtin_amdgcn_mfma_f32_16x16x32_bf16(
            af[mi], bfg[ni], acc[mi][ni], 0, 0, 0);
  };

  STAGE(0, 0);
  asm volatile("s_waitcnt vmcnt(0)" ::: "memory");
  __syncthreads();
  int cur = 0;
  for (int k0 = 32; k0 < K; k0 += 32) {
    STAGE(cur ^ 1, k0);
    COMPUTE(cur);
    asm volatile("s_waitcnt vmcnt(0)" ::: "memory");
    __syncthreads();
    cur ^= 1;
  }
  COMPUTE(cur);

  const int crow0 = (lane >> 4) * 4;
  const int ccol = lane & 15;
#pragma unroll
  for (int mi = 0; mi < 4; ++mi)
#pragma unroll
    for (int ni = 0; ni < 4; ++ni) {
      int gc = tileN + wn + ni * 16 + ccol;
      float bv = bias0[gc];
#pragma unroll
      for (int r = 0; r < 4; ++r) {
        int gr = tileM + wm + mi * 16 + crow0 + r;
        if (gr < M) {
          float v = acc[mi][ni][r] + bv;
          if (OUT_BF16)
            ((unsigned short*)C)[(size_t)gr * N + gc] = f2bf(v);
          else
            ((float*)C)[(size_t)gr * N + gc] = v;
        }
      }
    }
}

// ---------------- fused attention: local (x<16) + global partials (x>=16) ----------------
#define QBL 128
#define VT_PAD 168
#define P_PAD 72
__global__ __launch_bounds__(256, 2)
void attn_fused(const float* __restrict__ qcls,
                const unsigned short* __restrict__ Y,
                float* __restrict__ part,
                unsigned short* __restrict__ CTX) {
  const int h = blockIdx.y, b = blockIdx.z;
  const int tid = threadIdx.x, wid = tid >> 6, lane = tid & 63;

  __shared__ unsigned short Vt[64][VT_PAD];
  __shared__ unsigned short Pl[4][32][P_PAD];
  __shared__ float qf[64];
  __shared__ float ps[256];
  __shared__ float red[8];
  __shared__ float pacc[4][64];

  if (blockIdx.x >= 16) {
    // ===== global (cls) attention partial, key-chunk kc =====
    const int kc = blockIdx.x - 16;
    if (tid < 64) qf[tid] = qcls[b * EE + h * DD + tid];
    __syncthreads();

    int s = kc * 256 + tid;
    const short8* k8 = (const short8*)(Y + (size_t)(b * SS + s) * NY + h * DD);
    float dot = 0.0f;
#pragma unroll
    for (int i = 0; i < 8; ++i) {
      short8 kv = k8[i];
#pragma unroll
      for (int e = 0; e < 8; ++e) dot += qf[i * 8 + e] * bf2f((unsigned short)kv[e]);
    }
    dot *= 0.125f;

    float mx = dot;
    for (int o = 32; o; o >>= 1) mx = fmaxf(mx, __shfl_xor(mx, o));
    if ((tid & 63) == 0) red[tid >> 6] = mx;
    __syncthreads();
    float M = fmaxf(fmaxf(red[0], red[1]), fmaxf(red[2], red[3]));

    float p = __expf(dot - M);
    ps[tid] = p;
    float l = p;
    for (int o = 32; o; o >>= 1) l += __shfl_xor(l, o);
    if ((tid & 63) == 0) red[4 + (tid >> 6)] = l;
    __syncthreads();
    float L = red[4] + red[5] + red[6] + red[7];

    int g = tid >> 6, d = tid & 63;
    float acc = 0.0f;
    for (int sl = g; sl < 256; sl += 4)
      acc += ps[sl] * bf2f(Y[(size_t)(b * SS + kc * 256 + sl) * NY + 1024 + h * DD + d]);
    pacc[g][d] = acc;
    __syncthreads();
    if (g == 0) {
      float a = pacc[0][d] + pacc[1][d] + pacc[2][d] + pacc[3][d];
      float* pp = part + ((size_t)(b * HH + h) * 8 + kc) * 66;
      if (d == 0) { pp[0] = M; pp[1] = L; }
      pp[2 + d] = a;
    }
    return;
  }

  // ===== local attention via MFMA =====
  const int s0 = blockIdx.x * QBL;
  const int rl = lane & 15, g = lane >> 4;

  for (int task = tid; task < 640; task += 256) {
    int kp = task % 80, ch = task / 80;
    int k0 = kp * 2;
    int kg0 = min(max(s0 - 16 + k0, 0), SS - 1);
    int kg1 = min(max(s0 - 16 + k0 + 1, 0), SS - 1);
    short8 a = *(const short8*)&Y[(size_t)(b * SS + kg0) * NY + 4096 + h * DD + ch * 8];
    short8 bv = *(const short8*)&Y[(size_t)(b * SS + kg1) * NY + 4096 + h * DD + ch * 8];
#pragma unroll
    for (int e = 0; e < 8; ++e) {
      unsigned int w = (unsigned int)(unsigned short)a[e] |
                       ((unsigned int)(unsigned short)bv[e] << 16);
      *(unsigned int*)&Vt[ch * 8 + e][k0] = w;
    }
  }
  __syncthreads();

  const int qb = s0 + wid * 32;
  const int kb = qb - 16;

  short8 ak[4][2];
#pragma unroll
  for (int kt = 0; kt < 4; ++kt) {
    int kg = min(max(kb + kt * 16 + rl, 0), SS - 1);
    const unsigned short* kr = &Y[(size_t)(b * SS + kg) * NY + 3072 + h * DD + g * 8];
#pragma unroll
    for (int ks = 0; ks < 2; ++ks) ak[kt][ks] = *(const short8*)(kr + ks * 32);
  }
  short8 bq[2][2];
#pragma unroll
  for (int cc = 0; cc < 2; ++cc) {
    const unsigned short* qr = &Y[(size_t)(b * SS + qb + cc * 16 + rl) * NY + 2048 + h * DD + g * 8];
#pragma unroll
    for (int ks = 0; ks < 2; ++ks) bq[cc][ks] = *(const short8*)(qr + ks * 32);
  }

  f32x4 accs[4][2] = {};
#pragma unroll
  for (int kt = 0; kt < 4; ++kt)
#pragma unroll
    for (int cc = 0; cc < 2; ++cc)
#pragma unroll
      for (int ks = 0; ks < 2; ++ks)
        accs[kt][cc] = __builtin_amdgcn_mfma_f32_16x16x32_bf16(
            ak[kt][ks], bq[cc][ks], accs[kt][cc], 0, 0, 0);

  float mrow[2] = {-3e38f, -3e38f};
#pragma unroll
  for (int kt = 0; kt < 4; ++kt)
#pragma unroll
    for (int cc = 0; cc < 2; ++cc)
#pragma unroll
      for (int r = 0; r < 4; ++r) {
        int kg = kb + kt * 16 + 4 * g + r;
        int qg = qb + cc * 16 + rl;
        bool valid = (kg >= qg - 16) && (kg <= qg + 16) && (kg >= 1) && (kg < SS);
        float v = valid ? accs[kt][cc][r] : -3e38f;
        accs[kt][cc][r] = v;
        mrow[cc] = fmaxf(mrow[cc], v);
      }
#pragma unroll
  for (int cc = 0; cc < 2; ++cc) {
    float m = mrow[cc];
    m = fmaxf(m, __shfl_xor(m, 16));
    m = fmaxf(m, __shfl_xor(m, 32));
    mrow[cc] = m;
  }

  float zrow[2] = {0.0f, 0.0f};
#pragma unroll
  for (int cc = 0; cc < 2; ++cc)
#pragma unroll
    for (int kt = 0; kt < 4; ++kt) {
      ushort4 pw;
#pragma unroll
      for (int r = 0; r < 4; ++r) {
        float p = __expf((accs[kt][cc][r] - mrow[cc]) * 0.125f);
        zrow[cc] += p;
        ((unsigned short*)&pw)[r] = f2bf(p);
      }
      *(ushort4*)&Pl[wid][cc * 16 + rl][kt * 16 + 4 * g] = pw;
    }
#pragma unroll
  for (int cc = 0; cc < 2; ++cc) {
    float z = zrow[cc];
    z += __shfl_xor(z, 16);
    z += __shfl_xor(z, 32);
    zrow[cc] = 1.0f / z;
  }

  f32x4 accp[4][2] = {};
#pragma unroll
  for (int ks = 0; ks < 2; ++ks) {
    short8 bp[2];
#pragma unroll
    for (int cc = 0; cc < 2; ++cc)
      bp[cc] = *(const short8*)&Pl[wid][cc * 16 + rl][ks * 32 + g * 8];
#pragma unroll
    for (int mt = 0; mt < 4; ++mt) {
      short8 av = *(const short8*)&Vt[mt * 16 + rl][wid * 32 + ks * 32 + g * 8];
#pragma unroll
      for (int cc = 0; cc < 2; ++cc)
        accp[mt][cc] = __builtin_amdgcn_mfma_f32_16x16x32_bf16(
            av, bp[cc], accp[mt][cc], 0, 0, 0);
    }
  }

#pragma unroll
  for (int mt = 0; mt < 4; ++mt)
#pragma unroll
    for (int cc = 0; cc < 2; ++cc) {
      int token = qb + cc * 16 + rl;
      if (token == 0) {
        *(ushort4*)&CTX[(size_t)(b * SS) * EE + h * DD + mt * 16 + 4 * g] = ushort4{0, 0, 0, 0};
        continue;
      }
      ushort4 o;
#pragma unroll
      for (int r = 0; r < 4; ++r)
        ((unsigned short*)&o)[r] = f2bf(accp[mt][cc][r] * zrow[cc]);
      *(ushort4*)&CTX[(size_t)(b * SS + token) * EE + h * DD + mt * 16 + 4 * g] = o;
    }
}

// ---------------- cls output rows: combine partials + GEMV (one launch) ----------------
__global__ void gemv_cls(const float* __restrict__ part,
                         const float* __restrict__ Wc,     // out_w_cls [1024][1024]
                         const float* __restrict__ bc,
                         float* __restrict__ out) {
  __shared__ float ctx[EE];
  __shared__ float u[HH][8];
  const int b = blockIdx.x >> 8;
  const int tid = threadIdx.x;
  const float* pb = part + (size_t)b * HH * 8 * 66;
  if (tid < HH) {
    const float* pp = pb + tid * 8 * 66;
    float M = -1e30f;
#pragma unroll
    for (int i = 0; i < 8; ++i) M = fmaxf(M, pp[i * 66]);
    float Z = 0.0f, w[8];
#pragma unroll
    for (int i = 0; i < 8; ++i) { w[i] = __expf(pp[i * 66] - M); Z += w[i] * pp[i * 66 + 1]; }
#pragma unroll
    for (int i = 0; i < 8; ++i) u[tid][i] = w[i] / Z;
  }
  __syncthreads();
  for (int k = tid; k < EE; k += 256) {
    int hh = k >> 6, d = k & 63;
    const float* pp = pb + hh * 8 * 66 + 2 + d;
    float a = 0.0f;
#pragma unroll
    for (int i = 0; i < 8; ++i) a += u[hh][i] * pp[i * 66];
    ctx[k] = a;
  }
  __syncthreads();
  int n = (blockIdx.x & 255) * 4 + (tid >> 6);
  int lane = tid & 63;
  const float* w = Wc + (size_t)n * EE;
  float s = 0.0f;
  for (int k = lane; k < EE; k += 64) s += ctx[k] * w[k];
  for (int o = 32; o; o >>= 1) s += __shfl_xor(s, o);
  if (lane == 0) out[(size_t)b * SS * EE + n] = s + bc[n];
}

extern "C" void kernel_launch(void* const* d_in, const int* in_sizes, int n_in,
                              void* d_out, int out_size, void* d_ws, size_t ws_size,
                              hipStream_t stream) {
  const float* hs        = (const float*)d_in[0];
  const float* in_w_cls  = (const float*)d_in[1];
  const float* in_b_cls  = (const float*)d_in[2];
  const float* out_w_cls = (const float*)d_in[3];
  const float* out_b_cls = (const float*)d_in[4];
  const float* in_w_loc  = (const float*)d_in[5];
  const float* in_b_loc  = (const float*)d_in[6];
  const float* out_w_loc = (const float*)d_in[7];
  const float* out_b_loc = (const float*)d_in[8];
  float* out = (float*)d_out;

  const int M = BB * SS;  // 4096
  char* ws = (char*)d_ws;
  size_t off = 0;
  auto alloc = [&](size_t bytes) { char* p = ws + off; off += (bytes + 255) & ~(size_t)255; return p; };
  unsigned short* Xbf  = (unsigned short*)alloc((size_t)M * EE * 2);
  unsigned short* W    = (unsigned short*)alloc((size_t)NY * EE * 2);
  unsigned short* Wout = (unsigned short*)alloc((size_t)EE * EE * 2);
  unsigned short* Yb   = (unsigned short*)alloc((size_t)M * NY * 2);
  unsigned short* CTX  = (unsigned short*)alloc((size_t)M * EE * 2);
  float* qcls = (float*)alloc(2 * EE * 4);
  float* part = (float*)alloc((size_t)BB * HH * 8 * 66 * 4);

  // 1) fused casts + q_cls GEMV
  cast_all<<<10752, 256, 0, stream>>>(
      hs, Xbf,
      in_w_cls + (size_t)EE * EE, W,
      in_w_loc, W + (size_t)2048 * EE,
      out_w_loc, Wout,
      in_w_cls, in_b_cls, qcls);

  // 2) merged projection GEMM (r6-proven schedule, 256x320 tiles, 256 blocks)
  gemm8p<<<256, 512, 0, stream>>>(Xbf, W, in_b_cls, in_b_loc, Yb);

  // 3) fused attention (local MFMA + cls partials)
  attn_fused<<<dim3(24, HH, BB), 256, 0, stream>>>(qcls, Yb, part, CTX);

  // 4) local output projection (writes all rows of d_out; rows 0,2048 fixed next)
  {
    dim3 g3(M / 128, EE / 128);
    gemm_bt<0><<<g3, 256, 0, stream>>>(CTX, Wout, out_b_loc, out, M, EE, EE);
  }

  // 5) cls output rows (combine + GEMV fused)
  gemv_cls<<<512, 256, 0, stream>>>(part, out_w_cls, out_b_cls, out);
}

// Round 15
// 116.843 us; speedup vs baseline: 1.2821x; 1.0926x over previous
//
#include <hip/hip_runtime.h>

// Problem constants: B=2, S=2048, E=1024, H=16, D=64, WIN=16
#define BB 2
#define SS 2048
#define EE 1024
#define HH 16
#define DD 64
#define NY 5120   // merged projection output cols: [Kcls|Vcls|Qloc|Kloc|Vloc]

typedef __attribute__((ext_vector_type(8))) short short8;
typedef __attribute__((ext_vector_type(4))) float f32x4;

__device__ __forceinline__ float bf2f(unsigned short u) {
  union { unsigned int i; float f; } v; v.i = ((unsigned int)u) << 16; return v.f;
}
__device__ __forceinline__ unsigned short f2bf(float f) {
  unsigned int u = __float_as_uint(f);
  u += 0x7fff + ((u >> 16) & 1);   // RNE
  return (unsigned short)(u >> 16);
}
__device__ __forceinline__ void gload_lds16(const void* g, void* l) {
  __builtin_amdgcn_global_load_lds(
      (const __attribute__((address_space(1))) void*)g,
      (__attribute__((address_space(3))) void*)l, 16, 0, 0);
}

// ---------------- fused f32->bf16 casts + q_cls GEMV (one launch) ----------------
__global__ void cast_all(const float* __restrict__ s0, unsigned short* __restrict__ d0,
                         const float* __restrict__ s1, unsigned short* __restrict__ d1,
                         const float* __restrict__ s2, unsigned short* __restrict__ d2,
                         const float* __restrict__ s3, unsigned short* __restrict__ d3,
                         const float* __restrict__ in_w_cls,
                         const float* __restrict__ in_b_cls,
                         float* __restrict__ qcls) {
  int b = blockIdx.x;
  if (b >= 10240) {   // q_cls GEMV: 512 blocks x 4 rows
    int gw = (b - 10240) * 4 + (threadIdx.x >> 6);
    int lane = threadIdx.x & 63;
    int bb = gw >> 10, n = gw & 1023;
    const float* x = s0 + (size_t)bb * SS * EE;
    const float* w = in_w_cls + (size_t)n * EE;
    float s = 0.0f;
    for (int k = lane; k < EE; k += 64) s += x[k] * w[k];
    for (int o = 32; o; o >>= 1) s += __shfl_xor(s, o);
    if (lane == 0) qcls[bb * EE + n] = s + in_b_cls[n];
    return;
  }
  const float* s; unsigned short* d; int idx;
  if (b < 4096)      { s = s0; d = d0; idx = b; }
  else if (b < 6144) { s = s1; d = d1; idx = b - 4096; }
  else if (b < 9216) { s = s2; d = d2; idx = b - 6144; }
  else               { s = s3; d = d3; idx = b - 9216; }
  int i = (idx * 256 + threadIdx.x) * 4;
  float4 v = *reinterpret_cast<const float4*>(s + i);
  ushort4 o;
  o.x = f2bf(v.x); o.y = f2bf(v.y); o.z = f2bf(v.z); o.w = f2bf(v.w);
  *reinterpret_cast<ushort4*>(d + i) = o;
}

// ================= 8-phase 256x320 projection GEMM — A-frag pipelined =============
// Y[4096][5120] = Xbf[4096][1024] @ W[5120][1024]^T + bias
// r14 schedule + A-fragment double-buffer: each phase issues the NEXT phase's
// A-frag ds_reads; counted lgkmcnt(4) at P0/P1 so read latency hides under the
// previous MFMA cluster. One serial lgkm(0) per tile (P2, B kh-transition).
// Post-seam shadow pre-reads next tile's P0 frags (9 reads fly over the barrier).
// launch_bounds without min-wave hint: LDS 144KB pins 1 block/CU; allocator free.
#define SBAR __builtin_amdgcn_sched_barrier(0)
#define RAWBAR do { SBAR; __builtin_amdgcn_s_barrier(); SBAR; } while (0)
#define WAITVM0 do { asm volatile("s_waitcnt vmcnt(0)" ::: "memory"); SBAR; } while (0)
#define LGKM0 do { asm volatile("s_waitcnt lgkmcnt(0)" ::: "memory"); SBAR; } while (0)
#define LGKMW(n) do { asm volatile("s_waitcnt lgkmcnt(" #n ")" ::: "memory"); SBAR; } while (0)

#define MFMA20(FAX, MH)                                                              \
  _Pragma("unroll")                                                                  \
  for (int m = 0; m < 4; ++m)                                                        \
    _Pragma("unroll")                                                                \
    for (int n = 0; n < 5; ++n)                                                      \
      acc[(MH) * 4 + m][n] = __builtin_amdgcn_mfma_f32_16x16x32_bf16(                \
          FAX[m], bfr[n], acc[(MH) * 4 + m][n], 0, 0, 0);

__global__ __launch_bounds__(512)
void gemm8p(const unsigned short* __restrict__ Ag,   // [4096][1024]
            const unsigned short* __restrict__ Bg,   // [5120][1024]
            const float* __restrict__ bcls,
            const float* __restrict__ bloc,
            unsigned short* __restrict__ Yout) {     // [4096][5120]
  __shared__ unsigned short As2[2][256][64];   // 64 KiB
  __shared__ unsigned short Bs2[2][320][64];   // 80 KiB
  char* ldsA = (char*)As2;
  char* ldsB = (char*)Bs2;

  const int tid = threadIdx.x;
  const int wid = tid >> 6;
  const int lane = tid & 63;
  const int wm = wid >> 2;     // 0..1 -> 128-row slice
  const int wn = wid & 3;      // 0..3 -> 80-col slice
  const int rl = lane & 15;
  const int g4 = lane >> 4;

  int bid = blockIdx.x;
  bid = (bid & 7) * 32 + (bid >> 3);     // XCD swizzle, bijective (256 = 8*32)
  const int tileM = (bid & 15) * 256;
  const int tileN = (bid >> 4) * 320;

  f32x4 acc[8][5] = {};
  short8 FA0[4], FA1[4], bfr[5];

  auto SA = [&](int c, int kk, int i) {
    int flat = i * 8192 + tid * 16;
    int row = flat >> 7;
    int colb = (flat & 127) ^ ((row & 7) << 4);
    gload_lds16(Ag + (size_t)(tileM + row) * 1024 + kk + (colb >> 1),
                ldsA + c * 32768 + i * 8192 + wid * 1024);
  };
  auto SB = [&](int c, int kk, int j) {
    int flat = j * 8192 + tid * 16;
    int row = flat >> 7;
    int colb = (flat & 127) ^ ((row & 7) << 4);
    gload_lds16(Bg + (size_t)(tileN + row) * 1024 + kk + (colb >> 1),
                ldsB + c * 40960 + j * 8192 + wid * 1024);
  };
  auto DSA = [&](int c, int mh, int kh, short8* dst) {
#pragma unroll
    for (int m = 0; m < 4; ++m) {
      int row = wm * 128 + mh * 64 + m * 16 + rl;
      const char* base = ldsA + c * 32768 + row * 128;
      dst[m] = *(const short8*)(base + ((kh * 64 + g4 * 16) ^ ((row & 7) << 4)));
    }
  };
  auto DSB = [&](int c, int kh) {
#pragma unroll
    for (int n = 0; n < 5; ++n) {
      int row = wn * 80 + n * 16 + rl;
      const char* base = ldsB + c * 40960 + row * 128;
      bfr[n] = *(const short8*)(base + ((kh * 64 + g4 * 16) ^ ((row & 7) << 4)));
    }
  };

  // prologue: tile 0 -> buf0, then pre-read P0 frags (9 reads in flight)
  SA(0, 0, 0); SA(0, 0, 1); SA(0, 0, 2); SA(0, 0, 3);
  SB(0, 0, 0); SB(0, 0, 1); SB(0, 0, 2); SB(0, 0, 3); SB(0, 0, 4);
  WAITVM0;
  RAWBAR;
  DSB(0, 0); DSA(0, 0, 0, FA0);

#pragma unroll 1
  for (int t = 0; t < 16; ++t) {
    const int c = t & 1;
    const int kk = (t + 1) * 64;
    const bool st = (t < 15);
    // P0 (mh0,kh0): pre-read P1's A-frags
    DSA(c, 1, 0, FA1);
    if (st) { SA(c ^ 1, kk, 0); SA(c ^ 1, kk, 1); }
    RAWBAR; LGKMW(4);   // waits the 9 pre-seam reads; FA1's 4 stay in flight
    __builtin_amdgcn_s_setprio(1); MFMA20(FA0, 0); __builtin_amdgcn_s_setprio(0);
    RAWBAR;
    // P1 (mh1,kh0): pre-read P2's A-frags
    DSA(c, 0, 1, FA0);
    if (st) { SA(c ^ 1, kk, 2); SA(c ^ 1, kk, 3); }
    RAWBAR; LGKMW(4);   // waits FA1's 4; new 4 stay in flight
    __builtin_amdgcn_s_setprio(1); MFMA20(FA1, 1); __builtin_amdgcn_s_setprio(0);
    RAWBAR;
    // P2 (mh0,kh1): B kh-transition (single serial point) + P3's A-frags
    DSB(c, 1); DSA(c, 1, 1, FA1);
    if (st) { SB(c ^ 1, kk, 0); SB(c ^ 1, kk, 1); SB(c ^ 1, kk, 2); }
    RAWBAR; LGKM0;
    __builtin_amdgcn_s_setprio(1); MFMA20(FA0, 0); __builtin_amdgcn_s_setprio(0);
    RAWBAR;
    // P3 (mh1,kh1): all frags already resident
    if (st) { SB(c ^ 1, kk, 3); SB(c ^ 1, kk, 4); }
    RAWBAR;
    __builtin_amdgcn_s_setprio(1); MFMA20(FA1, 1); __builtin_amdgcn_s_setprio(0);
    if (st) WAITVM0;
    RAWBAR;
    // post-seam shadow: next tile's P0 frags (buf c^1 published by seam barrier)
    if (st) { DSB(c ^ 1, 0); DSA(c ^ 1, 0, 0, FA0); }
  }

  // epilogue: C row = tileM + wm*128 + m*16 + g4*4 + r, col = tileN + wn*80 + n*16 + rl
#pragma unroll
  for (int m = 0; m < 8; ++m)
#pragma unroll
    for (int n = 0; n < 5; ++n) {
      int gc = tileN + wn * 80 + n * 16 + rl;
      float bv = (gc < 2048) ? bcls[1024 + gc] : bloc[gc - 2048];
#pragma unroll
      for (int r = 0; r < 4; ++r) {
        int gr = tileM + wm * 128 + m * 16 + g4 * 4 + r;
        Yout[(size_t)gr * NY + gc] = f2bf(acc[m][n][r] + bv);
      }
    }
}

// ---------------- out-proj GEMM + cls-row GEMV fused (one launch) ----------------
// Blocks 0..255: 128x128 GEMM out = CTX @ Wout^T + b (rows 0,2048 skipped).
// Blocks 256..767: combine cls partials + GEMV -> out rows 0,2048.
__global__ __launch_bounds__(256, 4)
void gemm_out(const unsigned short* __restrict__ A,     // CTX [4096][1024]
              const unsigned short* __restrict__ B,     // Wout [1024][1024]
              const float* __restrict__ bias0,          // out_b_loc
              float* __restrict__ C,                    // out [4096][1024]
              const float* __restrict__ part,           // cls partials
              const float* __restrict__ Wc,             // out_w_cls
              const float* __restrict__ bc) {           // out_b_cls
  __shared__ unsigned short As[2][128 * 32];
  __shared__ unsigned short Bs[2][128 * 32];
  __shared__ float ctx[EE];
  __shared__ float u[HH][8];

  const int tid = threadIdx.x;

  if (blockIdx.x >= 256) {
    // ===== cls rows: combine 8 chunk-partials then GEMV =====
    const int cid = blockIdx.x - 256;        // 0..511
    const int b = cid >> 8;
    const float* pb = part + (size_t)b * HH * 8 * 66;
    if (tid < HH) {
      const float* pp = pb + tid * 8 * 66;
      float M = -1e30f;
#pragma unroll
      for (int i = 0; i < 8; ++i) M = fmaxf(M, pp[i * 66]);
      float Z = 0.0f, w[8];
#pragma unroll
      for (int i = 0; i < 8; ++i) { w[i] = __expf(pp[i * 66] - M); Z += w[i] * pp[i * 66 + 1]; }
#pragma unroll
      for (int i = 0; i < 8; ++i) u[tid][i] = w[i] / Z;
    }
    __syncthreads();
    for (int k = tid; k < EE; k += 256) {
      int hh = k >> 6, d = k & 63;
      const float* pp = pb + hh * 8 * 66 + 2 + d;
      float a = 0.0f;
#pragma unroll
      for (int i = 0; i < 8; ++i) a += u[hh][i] * pp[i * 66];
      ctx[k] = a;
    }
    __syncthreads();
    int n = (cid & 255) * 4 + (tid >> 6);
    int lane = tid & 63;
    const float* w = Wc + (size_t)n * EE;
    float s = 0.0f;
    for (int k = lane; k < EE; k += 64) s += ctx[k] * w[k];
    for (int o = 32; o; o >>= 1) s += __shfl_xor(s, o);
    if (lane == 0) C[(size_t)b * SS * EE + n] = s + bc[n];
    return;
  }

  // ===== 128x128 GEMM (proven 2-phase skeleton), M=4096 N=1024 K=1024 =====
  const int wid = tid >> 6;
  const int lane = tid & 63;
  int bid = blockIdx.x;
  bid = (bid & 7) * 32 + (bid >> 3);       // XCD swizzle over 256
  const int tileM = (bid % 32) * 128;
  const int tileN = (bid / 32) * 128;

  const int wm = (wid >> 1) * 64;
  const int wn = (wid & 1) * 64;
  const int rl = lane & 15;
  const int kc = (lane >> 4) * 8;

  f32x4 acc[4][4] = {};

  const int srow = tid >> 2;
  const int scol = (tid & 3) * 8;
  const unsigned short* gA = A + (size_t)(tileM + srow) * EE + scol;
  const unsigned short* gB = B + (size_t)(tileN + srow) * EE + scol;
  char* lA = (char*)As + wid * 1024;
  char* lB = (char*)Bs + wid * 1024;

  auto STAGE = [&](int buf, int k0) {
    gload_lds16(gA + k0, lA + buf * 8192);
    gload_lds16(gA + (size_t)64 * EE + k0, lA + buf * 8192 + 4096);
    gload_lds16(gB + k0, lB + buf * 8192);
    gload_lds16(gB + (size_t)64 * EE + k0, lB + buf * 8192 + 4096);
  };
  auto COMPUTE = [&](int buf) {
    const unsigned short* as = As[buf];
    const unsigned short* bs = Bs[buf];
    short8 af[4], bfg[4];
#pragma unroll
    for (int mi = 0; mi < 4; ++mi)
      af[mi] = *reinterpret_cast<const short8*>(&as[(wm + mi * 16 + rl) * 32 + kc]);
#pragma unroll
    for (int ni = 0; ni < 4; ++ni)
      bfg[ni] = *reinterpret_cast<const short8*>(&bs[(wn + ni * 16 + rl) * 32 + kc]);
#pragma unroll
    for (int mi = 0; mi < 4; ++mi)
#pragma unroll
      for (int ni = 0; ni < 4; ++ni)
        acc[mi][ni] = __builtin_amdgcn_mfma_f32_16x16x32_bf16(
            af[mi], bfg[ni], acc[mi][ni], 0, 0, 0);
  };

  STAGE(0, 0);
  asm volatile("s_waitcnt vmcnt(0)" ::: "memory");
  __syncthreads();
  int cur = 0;
  for (int k0 = 32; k0 < EE; k0 += 32) {
    STAGE(cur ^ 1, k0);
    COMPUTE(cur);
    asm volatile("s_waitcnt vmcnt(0)" ::: "memory");
    __syncthreads();
    cur ^= 1;
  }
  COMPUTE(cur);

  const int crow0 = (lane >> 4) * 4;
  const int ccol = lane & 15;
#pragma unroll
  for (int mi = 0; mi < 4; ++mi)
#pragma unroll
    for (int ni = 0; ni < 4; ++ni) {
      int gc = tileN + wn + ni * 16 + ccol;
      float bv = bias0[gc];
#pragma unroll
      for (int r = 0; r < 4; ++r) {
        int gr = tileM + wm + mi * 16 + crow0 + r;
        if (gr & 2047)   // rows 0 and 2048 belong to the cls blocks
          C[(size_t)gr * EE + gc] = acc[mi][ni][r] + bv;
      }
    }
}

// ---------------- fused attention: local (x<16) + global partials (x>=16) ----------------
#define QBL 128
#define VT_PAD 168
#define P_PAD 72
__global__ __launch_bounds__(256, 2)
void attn_fused(const float* __restrict__ qcls,
                const unsigned short* __restrict__ Y,
                float* __restrict__ part,
                unsigned short* __restrict__ CTX) {
  const int h = blockIdx.y, b = blockIdx.z;
  const int tid = threadIdx.x, wid = tid >> 6, lane = tid & 63;

  __shared__ unsigned short Vt[64][VT_PAD];
  __shared__ unsigned short Pl[4][32][P_PAD];
  __shared__ float qf[64];
  __shared__ float ps[256];
  __shared__ float red[8];
  __shared__ float pacc[4][64];

  if (blockIdx.x >= 16) {
    // ===== global (cls) attention partial, key-chunk kc =====
    const int kc = blockIdx.x - 16;
    if (tid < 64) qf[tid] = qcls[b * EE + h * DD + tid];
    __syncthreads();

    int s = kc * 256 + tid;
    const short8* k8 = (const short8*)(Y + (size_t)(b * SS + s) * NY + h * DD);
    float dot = 0.0f;
#pragma unroll
    for (int i = 0; i < 8; ++i) {
      short8 kv = k8[i];
#pragma unroll
      for (int e = 0; e < 8; ++e) dot += qf[i * 8 + e] * bf2f((unsigned short)kv[e]);
    }
    dot *= 0.125f;

    float mx = dot;
    for (int o = 32; o; o >>= 1) mx = fmaxf(mx, __shfl_xor(mx, o));
    if ((tid & 63) == 0) red[tid >> 6] = mx;
    __syncthreads();
    float M = fmaxf(fmaxf(red[0], red[1]), fmaxf(red[2], red[3]));

    float p = __expf(dot - M);
    ps[tid] = p;
    float l = p;
    for (int o = 32; o; o >>= 1) l += __shfl_xor(l, o);
    if ((tid & 63) == 0) red[4 + (tid >> 6)] = l;
    __syncthreads();
    float L = red[4] + red[5] + red[6] + red[7];

    int g = tid >> 6, d = tid & 63;
    float acc = 0.0f;
    for (int sl = g; sl < 256; sl += 4)
      acc += ps[sl] * bf2f(Y[(size_t)(b * SS + kc * 256 + sl) * NY + 1024 + h * DD + d]);
    pacc[g][d] = acc;
    __syncthreads();
    if (g == 0) {
      float a = pacc[0][d] + pacc[1][d] + pacc[2][d] + pacc[3][d];
      float* pp = part + ((size_t)(b * HH + h) * 8 + kc) * 66;
      if (d == 0) { pp[0] = M; pp[1] = L; }
      pp[2 + d] = a;
    }
    return;
  }

  // ===== local attention via MFMA =====
  const int s0 = blockIdx.x * QBL;
  const int rl = lane & 15, g = lane >> 4;

  for (int task = tid; task < 640; task += 256) {
    int kp = task % 80, ch = task / 80;
    int k0 = kp * 2;
    int kg0 = min(max(s0 - 16 + k0, 0), SS - 1);
    int kg1 = min(max(s0 - 16 + k0 + 1, 0), SS - 1);
    short8 a = *(const short8*)&Y[(size_t)(b * SS + kg0) * NY + 4096 + h * DD + ch * 8];
    short8 bv = *(const short8*)&Y[(size_t)(b * SS + kg1) * NY + 4096 + h * DD + ch * 8];
#pragma unroll
    for (int e = 0; e < 8; ++e) {
      unsigned int w = (unsigned int)(unsigned short)a[e] |
                       ((unsigned int)(unsigned short)bv[e] << 16);
      *(unsigned int*)&Vt[ch * 8 + e][k0] = w;
    }
  }
  __syncthreads();

  const int qb = s0 + wid * 32;
  const int kb = qb - 16;

  short8 ak[4][2];
#pragma unroll
  for (int kt = 0; kt < 4; ++kt) {
    int kg = min(max(kb + kt * 16 + rl, 0), SS - 1);
    const unsigned short* kr = &Y[(size_t)(b * SS + kg) * NY + 3072 + h * DD + g * 8];
#pragma unroll
    for (int ks = 0; ks < 2; ++ks) ak[kt][ks] = *(const short8*)(kr + ks * 32);
  }
  short8 bq[2][2];
#pragma unroll
  for (int cc = 0; cc < 2; ++cc) {
    const unsigned short* qr = &Y[(size_t)(b * SS + qb + cc * 16 + rl) * NY + 2048 + h * DD + g * 8];
#pragma unroll
    for (int ks = 0; ks < 2; ++ks) bq[cc][ks] = *(const short8*)(qr + ks * 32);
  }

  f32x4 accs[4][2] = {};
#pragma unroll
  for (int kt = 0; kt < 4; ++kt)
#pragma unroll
    for (int cc = 0; cc < 2; ++cc)
#pragma unroll
      for (int ks = 0; ks < 2; ++ks)
        accs[kt][cc] = __builtin_amdgcn_mfma_f32_16x16x32_bf16(
            ak[kt][ks], bq[cc][ks], accs[kt][cc], 0, 0, 0);

  float mrow[2] = {-3e38f, -3e38f};
#pragma unroll
  for (int kt = 0; kt < 4; ++kt)
#pragma unroll
    for (int cc = 0; cc < 2; ++cc)
#pragma unroll
      for (int r = 0; r < 4; ++r) {
        int kg = kb + kt * 16 + 4 * g + r;
        int qg = qb + cc * 16 + rl;
        bool valid = (kg >= qg - 16) && (kg <= qg + 16) && (kg >= 1) && (kg < SS);
        float v = valid ? accs[kt][cc][r] : -3e38f;
        accs[kt][cc][r] = v;
        mrow[cc] = fmaxf(mrow[cc], v);
      }
#pragma unroll
  for (int cc = 0; cc < 2; ++cc) {
    float m = mrow[cc];
    m = fmaxf(m, __shfl_xor(m, 16));
    m = fmaxf(m, __shfl_xor(m, 32));
    mrow[cc] = m;
  }

  float zrow[2] = {0.0f, 0.0f};
#pragma unroll
  for (int cc = 0; cc < 2; ++cc)
#pragma unroll
    for (int kt = 0; kt < 4; ++kt) {
      ushort4 pw;
#pragma unroll
      for (int r = 0; r < 4; ++r) {
        float p = __expf((accs[kt][cc][r] - mrow[cc]) * 0.125f);
        zrow[cc] += p;
        ((unsigned short*)&pw)[r] = f2bf(p);
      }
      *(ushort4*)&Pl[wid][cc * 16 + rl][kt * 16 + 4 * g] = pw;
    }
#pragma unroll
  for (int cc = 0; cc < 2; ++cc) {
    float z = zrow[cc];
    z += __shfl_xor(z, 16);
    z += __shfl_xor(z, 32);
    zrow[cc] = 1.0f / z;
  }

  f32x4 accp[4][2] = {};
#pragma unroll
  for (int ks = 0; ks < 2; ++ks) {
    short8 bp[2];
#pragma unroll
    for (int cc = 0; cc < 2; ++cc)
      bp[cc] = *(const short8*)&Pl[wid][cc * 16 + rl][ks * 32 + g * 8];
#pragma unroll
    for (int mt = 0; mt < 4; ++mt) {
      short8 av = *(const short8*)&Vt[mt * 16 + rl][wid * 32 + ks * 32 + g * 8];
#pragma unroll
      for (int cc = 0; cc < 2; ++cc)
        accp[mt][cc] = __builtin_amdgcn_mfma_f32_16x16x32_bf16(
            av, bp[cc], accp[mt][cc], 0, 0, 0);
    }
  }

#pragma unroll
  for (int mt = 0; mt < 4; ++mt)
#pragma unroll
    for (int cc = 0; cc < 2; ++cc) {
      int token = qb + cc * 16 + rl;
      if (token == 0) {
        *(ushort4*)&CTX[(size_t)(b * SS) * EE + h * DD + mt * 16 + 4 * g] = ushort4{0, 0, 0, 0};
        continue;
      }
      ushort4 o;
#pragma unroll
      for (int r = 0; r < 4; ++r)
        ((unsigned short*)&o)[r] = f2bf(accp[mt][cc][r] * zrow[cc]);
      *(ushort4*)&CTX[(size_t)(b * SS + token) * EE + h * DD + mt * 16 + 4 * g] = o;
    }
}

extern "C" void kernel_launch(void* const* d_in, const int* in_sizes, int n_in,
                              void* d_out, int out_size, void* d_ws, size_t ws_size,
                              hipStream_t stream) {
  const float* hs        = (const float*)d_in[0];
  const float* in_w_cls  = (const float*)d_in[1];
  const float* in_b_cls  = (const float*)d_in[2];
  const float* out_w_cls = (const float*)d_in[3];
  const float* out_b_cls = (const float*)d_in[4];
  const float* in_w_loc  = (const float*)d_in[5];
  const float* in_b_loc  = (const float*)d_in[6];
  const float* out_w_loc = (const float*)d_in[7];
  const float* out_b_loc = (const float*)d_in[8];
  float* out = (float*)d_out;

  const int M = BB * SS;  // 4096
  char* ws = (char*)d_ws;
  size_t off = 0;
  auto alloc = [&](size_t bytes) { char* p = ws + off; off += (bytes + 255) & ~(size_t)255; return p; };
  unsigned short* Xbf  = (unsigned short*)alloc((size_t)M * EE * 2);
  unsigned short* W    = (unsigned short*)alloc((size_t)NY * EE * 2);
  unsigned short* Wout = (unsigned short*)alloc((size_t)EE * EE * 2);
  unsigned short* Yb   = (unsigned short*)alloc((size_t)M * NY * 2);
  unsigned short* CTX  = (unsigned short*)alloc((size_t)M * EE * 2);
  float* qcls = (float*)alloc(2 * EE * 4);
  float* part = (float*)alloc((size_t)BB * HH * 8 * 66 * 4);

  // 1) fused casts + q_cls GEMV
  cast_all<<<10752, 256, 0, stream>>>(
      hs, Xbf,
      in_w_cls + (size_t)EE * EE, W,
      in_w_loc, W + (size_t)2048 * EE,
      out_w_loc, Wout,
      in_w_cls, in_b_cls, qcls);

  // 2) merged projection GEMM (A-frag pipelined, 256x320 tiles, 256 blocks)
  gemm8p<<<256, 512, 0, stream>>>(Xbf, W, in_b_cls, in_b_loc, Yb);

  // 3) fused attention (local MFMA + cls partials)
  attn_fused<<<dim3(24, HH, BB), 256, 0, stream>>>(qcls, Yb, part, CTX);

  // 4) out-proj GEMM + cls rows (one launch; GEMM skips rows 0/2048)
  gemm_out<<<768, 256, 0, stream>>>(CTX, Wout, out_b_loc, out,
                                    part, out_w_cls, out_b_cls);
}

// Round 17
// 103.664 us; speedup vs baseline: 1.4451x; 1.1271x over previous
//
#include <hip/hip_runtime.h>

// Problem constants: B=2, S=2048, E=1024, H=16, D=64, WIN=16
#define BB 2
#define SS 2048
#define EE 1024
#define HH 16
#define DD 64
#define NY 5120   // merged projection output cols: [Kcls|Vcls|Qloc|Kloc|Vloc]

typedef __attribute__((ext_vector_type(8))) short short8;
typedef __attribute__((ext_vector_type(4))) float f32x4;

__device__ __forceinline__ float bf2f(unsigned short u) {
  union { unsigned int i; float f; } v; v.i = ((unsigned int)u) << 16; return v.f;
}
__device__ __forceinline__ unsigned short f2bf(float f) {
  unsigned int u = __float_as_uint(f);
  u += 0x7fff + ((u >> 16) & 1);   // RNE
  return (unsigned short)(u >> 16);
}
__device__ __forceinline__ void gload_lds16(const void* g, void* l) {
  __builtin_amdgcn_global_load_lds(
      (const __attribute__((address_space(1))) void*)g,
      (__attribute__((address_space(3))) void*)l, 16, 0, 0);
}

// ---------------- fused f32->bf16 casts + q_cls GEMV (one launch) ----------------
__global__ void cast_all(const float* __restrict__ s0, unsigned short* __restrict__ d0,
                         const float* __restrict__ s1, unsigned short* __restrict__ d1,
                         const float* __restrict__ s2, unsigned short* __restrict__ d2,
                         const float* __restrict__ s3, unsigned short* __restrict__ d3,
                         const float* __restrict__ in_w_cls,
                         const float* __restrict__ in_b_cls,
                         float* __restrict__ qcls) {
  int b = blockIdx.x;
  if (b >= 10240) {   // q_cls GEMV: 512 blocks x 4 rows
    int gw = (b - 10240) * 4 + (threadIdx.x >> 6);
    int lane = threadIdx.x & 63;
    int bb = gw >> 10, n = gw & 1023;
    const float* x = s0 + (size_t)bb * SS * EE;
    const float* w = in_w_cls + (size_t)n * EE;
    float s = 0.0f;
    for (int k = lane; k < EE; k += 64) s += x[k] * w[k];
    for (int o = 32; o; o >>= 1) s += __shfl_xor(s, o);
    if (lane == 0) qcls[bb * EE + n] = s + in_b_cls[n];
    return;
  }
  const float* s; unsigned short* d; int idx;
  if (b < 4096)      { s = s0; d = d0; idx = b; }
  else if (b < 6144) { s = s1; d = d1; idx = b - 4096; }
  else if (b < 9216) { s = s2; d = d2; idx = b - 6144; }
  else               { s = s3; d = d3; idx = b - 9216; }
  int i = (idx * 256 + threadIdx.x) * 4;
  float4 v = *reinterpret_cast<const float4*>(s + i);
  ushort4 o;
  o.x = f2bf(v.x); o.y = f2bf(v.y); o.z = f2bf(v.z); o.w = f2bf(v.w);
  *reinterpret_cast<ushort4*>(d + i) = o;
}

// ================= 8-phase 256x320 projection GEMM — A-frag pipelined (r15) =======
// Y[4096][5120] = Xbf[4096][1024] @ W[5120][1024]^T + bias
// Proven deterministic: full vmcnt(0) seam publishes ALL waves' staging before the
// barrier (per-wave counted seams race — r16 lesson). A-fragment double-buffer with
// counted lgkmcnt(4) at P0/P1; post-seam shadow pre-reads next tile's P0 frags.
#define SBAR __builtin_amdgcn_sched_barrier(0)
#define RAWBAR do { SBAR; __builtin_amdgcn_s_barrier(); SBAR; } while (0)
#define WAITVM0 do { asm volatile("s_waitcnt vmcnt(0)" ::: "memory"); SBAR; } while (0)
#define LGKM0 do { asm volatile("s_waitcnt lgkmcnt(0)" ::: "memory"); SBAR; } while (0)
#define LGKMW(n) do { asm volatile("s_waitcnt lgkmcnt(" #n ")" ::: "memory"); SBAR; } while (0)

#define MFMA20(FAX, MH)                                                              \
  _Pragma("unroll")                                                                  \
  for (int m = 0; m < 4; ++m)                                                        \
    _Pragma("unroll")                                                                \
    for (int n = 0; n < 5; ++n)                                                      \
      acc[(MH) * 4 + m][n] = __builtin_amdgcn_mfma_f32_16x16x32_bf16(                \
          FAX[m], bfr[n], acc[(MH) * 4 + m][n], 0, 0, 0);

__global__ __launch_bounds__(512)
void gemm8p(const unsigned short* __restrict__ Ag,   // [4096][1024]
            const unsigned short* __restrict__ Bg,   // [5120][1024]
            const float* __restrict__ bcls,
            const float* __restrict__ bloc,
            unsigned short* __restrict__ Yout) {     // [4096][5120]
  __shared__ unsigned short As2[2][256][64];   // 64 KiB
  __shared__ unsigned short Bs2[2][320][64];   // 80 KiB
  char* ldsA = (char*)As2;
  char* ldsB = (char*)Bs2;

  const int tid = threadIdx.x;
  const int wid = tid >> 6;
  const int lane = tid & 63;
  const int wm = wid >> 2;     // 0..1 -> 128-row slice
  const int wn = wid & 3;      // 0..3 -> 80-col slice
  const int rl = lane & 15;
  const int g4 = lane >> 4;

  int bid = blockIdx.x;
  bid = (bid & 7) * 32 + (bid >> 3);     // XCD swizzle, bijective (256 = 8*32)
  const int tileM = (bid & 15) * 256;
  const int tileN = (bid >> 4) * 320;

  f32x4 acc[8][5] = {};
  short8 FA0[4], FA1[4], bfr[5];

  auto SA = [&](int c, int kk, int i) {
    int flat = i * 8192 + tid * 16;
    int row = flat >> 7;
    int colb = (flat & 127) ^ ((row & 7) << 4);
    gload_lds16(Ag + (size_t)(tileM + row) * 1024 + kk + (colb >> 1),
                ldsA + c * 32768 + i * 8192 + wid * 1024);
  };
  auto SB = [&](int c, int kk, int j) {
    int flat = j * 8192 + tid * 16;
    int row = flat >> 7;
    int colb = (flat & 127) ^ ((row & 7) << 4);
    gload_lds16(Bg + (size_t)(tileN + row) * 1024 + kk + (colb >> 1),
                ldsB + c * 40960 + j * 8192 + wid * 1024);
  };
  auto DSA = [&](int c, int mh, int kh, short8* dst) {
#pragma unroll
    for (int m = 0; m < 4; ++m) {
      int row = wm * 128 + mh * 64 + m * 16 + rl;
      const char* base = ldsA + c * 32768 + row * 128;
      dst[m] = *(const short8*)(base + ((kh * 64 + g4 * 16) ^ ((row & 7) << 4)));
    }
  };
  auto DSB = [&](int c, int kh) {
#pragma unroll
    for (int n = 0; n < 5; ++n) {
      int row = wn * 80 + n * 16 + rl;
      const char* base = ldsB + c * 40960 + row * 128;
      bfr[n] = *(const short8*)(base + ((kh * 64 + g4 * 16) ^ ((row & 7) << 4)));
    }
  };

  // prologue: tile 0 -> buf0, then pre-read P0 frags (9 reads in flight)
  SA(0, 0, 0); SA(0, 0, 1); SA(0, 0, 2); SA(0, 0, 3);
  SB(0, 0, 0); SB(0, 0, 1); SB(0, 0, 2); SB(0, 0, 3); SB(0, 0, 4);
  WAITVM0;
  RAWBAR;
  DSB(0, 0); DSA(0, 0, 0, FA0);

#pragma unroll 1
  for (int t = 0; t < 16; ++t) {
    const int c = t & 1;
    const int kk = (t + 1) * 64;
    const bool st = (t < 15);
    // P0 (mh0,kh0): pre-read P1's A-frags
    DSA(c, 1, 0, FA1);
    if (st) { SA(c ^ 1, kk, 0); SA(c ^ 1, kk, 1); }
    RAWBAR; LGKMW(4);   // waits the 9 pre-seam reads; FA1's 4 stay in flight
    __builtin_amdgcn_s_setprio(1); MFMA20(FA0, 0); __builtin_amdgcn_s_setprio(0);
    RAWBAR;
    // P1 (mh1,kh0): pre-read P2's A-frags
    DSA(c, 0, 1, FA0);
    if (st) { SA(c ^ 1, kk, 2); SA(c ^ 1, kk, 3); }
    RAWBAR; LGKMW(4);   // waits FA1's 4; new 4 stay in flight
    __builtin_amdgcn_s_setprio(1); MFMA20(FA1, 1); __builtin_amdgcn_s_setprio(0);
    RAWBAR;
    // P2 (mh0,kh1): B kh-transition (single serial point) + P3's A-frags
    DSB(c, 1); DSA(c, 1, 1, FA1);
    if (st) { SB(c ^ 1, kk, 0); SB(c ^ 1, kk, 1); SB(c ^ 1, kk, 2); }
    RAWBAR; LGKM0;
    __builtin_amdgcn_s_setprio(1); MFMA20(FA0, 0); __builtin_amdgcn_s_setprio(0);
    RAWBAR;
    // P3 (mh1,kh1): all frags already resident
    if (st) { SB(c ^ 1, kk, 3); SB(c ^ 1, kk, 4); }
    RAWBAR;
    __builtin_amdgcn_s_setprio(1); MFMA20(FA1, 1); __builtin_amdgcn_s_setprio(0);
    if (st) WAITVM0;    // full drain: publishes ALL waves' staging (no race)
    RAWBAR;
    // post-seam shadow: next tile's P0 frags (buf c^1 published by seam barrier)
    if (st) { DSB(c ^ 1, 0); DSA(c ^ 1, 0, 0, FA0); }
  }

  // epilogue: C row = tileM + wm*128 + m*16 + g4*4 + r, col = tileN + wn*80 + n*16 + rl
#pragma unroll
  for (int m = 0; m < 8; ++m)
#pragma unroll
    for (int n = 0; n < 5; ++n) {
      int gc = tileN + wn * 80 + n * 16 + rl;
      float bv = (gc < 2048) ? bcls[1024 + gc] : bloc[gc - 2048];
#pragma unroll
      for (int r = 0; r < 4; ++r) {
        int gr = tileM + wm * 128 + m * 16 + g4 * 4 + r;
        Yout[(size_t)gr * NY + gc] = f2bf(acc[m][n][r] + bv);
      }
    }
}

// ---------------- out-proj GEMM + cls-row GEMV fused (one launch) ----------------
__global__ __launch_bounds__(256, 4)
void gemm_out(const unsigned short* __restrict__ A,     // CTX [4096][1024]
              const unsigned short* __restrict__ B,     // Wout [1024][1024]
              const float* __restrict__ bias0,          // out_b_loc
              float* __restrict__ C,                    // out [4096][1024]
              const float* __restrict__ part,           // cls partials
              const float* __restrict__ Wc,             // out_w_cls
              const float* __restrict__ bc) {           // out_b_cls
  __shared__ unsigned short As[2][128 * 32];
  __shared__ unsigned short Bs[2][128 * 32];
  __shared__ float ctx[EE];
  __shared__ float u[HH][8];

  const int tid = threadIdx.x;

  if (blockIdx.x >= 256) {
    const int cid = blockIdx.x - 256;        // 0..511
    const int b = cid >> 8;
    const float* pb = part + (size_t)b * HH * 8 * 66;
    if (tid < HH) {
      const float* pp = pb + tid * 8 * 66;
      float M = -1e30f;
#pragma unroll
      for (int i = 0; i < 8; ++i) M = fmaxf(M, pp[i * 66]);
      float Z = 0.0f, w[8];
#pragma unroll
      for (int i = 0; i < 8; ++i) { w[i] = __expf(pp[i * 66] - M); Z += w[i] * pp[i * 66 + 1]; }
#pragma unroll
      for (int i = 0; i < 8; ++i) u[tid][i] = w[i] / Z;
    }
    __syncthreads();
    for (int k = tid; k < EE; k += 256) {
      int hh = k >> 6, d = k & 63;
      const float* pp = pb + hh * 8 * 66 + 2 + d;
      float a = 0.0f;
#pragma unroll
      for (int i = 0; i < 8; ++i) a += u[hh][i] * pp[i * 66];
      ctx[k] = a;
    }
    __syncthreads();
    int n = (cid & 255) * 4 + (tid >> 6);
    int lane = tid & 63;
    const float* w = Wc + (size_t)n * EE;
    float s = 0.0f;
    for (int k = lane; k < EE; k += 64) s += ctx[k] * w[k];
    for (int o = 32; o; o >>= 1) s += __shfl_xor(s, o);
    if (lane == 0) C[(size_t)b * SS * EE + n] = s + bc[n];
    return;
  }

  const int wid = tid >> 6;
  const int lane = tid & 63;
  int bid = blockIdx.x;
  bid = (bid & 7) * 32 + (bid >> 3);       // XCD swizzle over 256
  const int tileM = (bid % 32) * 128;
  const int tileN = (bid / 32) * 128;

  const int wm = (wid >> 1) * 64;
  const int wn = (wid & 1) * 64;
  const int rl = lane & 15;
  const int kc = (lane >> 4) * 8;

  f32x4 acc[4][4] = {};

  const int srow = tid >> 2;
  const int scol = (tid & 3) * 8;
  const unsigned short* gA = A + (size_t)(tileM + srow) * EE + scol;
  const unsigned short* gB = B + (size_t)(tileN + srow) * EE + scol;
  char* lA = (char*)As + wid * 1024;
  char* lB = (char*)Bs + wid * 1024;

  auto STAGE = [&](int buf, int k0) {
    gload_lds16(gA + k0, lA + buf * 8192);
    gload_lds16(gA + (size_t)64 * EE + k0, lA + buf * 8192 + 4096);
    gload_lds16(gB + k0, lB + buf * 8192);
    gload_lds16(gB + (size_t)64 * EE + k0, lB + buf * 8192 + 4096);
  };
  auto COMPUTE = [&](int buf) {
    const unsigned short* as = As[buf];
    const unsigned short* bs = Bs[buf];
    short8 af[4], bfg[4];
#pragma unroll
    for (int mi = 0; mi < 4; ++mi)
      af[mi] = *reinterpret_cast<const short8*>(&as[(wm + mi * 16 + rl) * 32 + kc]);
#pragma unroll
    for (int ni = 0; ni < 4; ++ni)
      bfg[ni] = *reinterpret_cast<const short8*>(&bs[(wn + ni * 16 + rl) * 32 + kc]);
#pragma unroll
    for (int mi = 0; mi < 4; ++mi)
#pragma unroll
      for (int ni = 0; ni < 4; ++ni)
        acc[mi][ni] = __builtin_amdgcn_mfma_f32_16x16x32_bf16(
            af[mi], bfg[ni], acc[mi][ni], 0, 0, 0);
  };

  STAGE(0, 0);
  asm volatile("s_waitcnt vmcnt(0)" ::: "memory");
  __syncthreads();
  int cur = 0;
  for (int k0 = 32; k0 < EE; k0 += 32) {
    STAGE(cur ^ 1, k0);
    COMPUTE(cur);
    asm volatile("s_waitcnt vmcnt(0)" ::: "memory");
    __syncthreads();
    cur ^= 1;
  }
  COMPUTE(cur);

  const int crow0 = (lane >> 4) * 4;
  const int ccol = lane & 15;
#pragma unroll
  for (int mi = 0; mi < 4; ++mi)
#pragma unroll
    for (int ni = 0; ni < 4; ++ni) {
      int gc = tileN + wn + ni * 16 + ccol;
      float bv = bias0[gc];
#pragma unroll
      for (int r = 0; r < 4; ++r) {
        int gr = tileM + wm + mi * 16 + crow0 + r;
        if (gr & 2047)   // rows 0 and 2048 belong to the cls blocks
          C[(size_t)gr * EE + gc] = acc[mi][ni][r] + bv;
      }
    }
}

// ---------------- fused attention: local (x<16) + global partials (x>=16) ----------------
#define QBL 128
#define VT_PAD 168
#define P_PAD 72
__global__ __launch_bounds__(256, 2)
void attn_fused(const float* __restrict__ qcls,
                const unsigned short* __restrict__ Y,
                float* __restrict__ part,
                unsigned short* __restrict__ CTX) {
  const int h = blockIdx.y, b = blockIdx.z;
  const int tid = threadIdx.x, wid = tid >> 6, lane = tid & 63;

  __shared__ unsigned short Vt[64][VT_PAD];
  __shared__ unsigned short Pl[4][32][P_PAD];
  __shared__ float qf[64];
  __shared__ float ps[256];
  __shared__ float red[8];
  __shared__ float pacc[4][64];

  if (blockIdx.x >= 16) {
    // ===== global (cls) attention partial, key-chunk kc =====
    const int kc = blockIdx.x - 16;
    if (tid < 64) qf[tid] = qcls[b * EE + h * DD + tid];
    __syncthreads();

    int s = kc * 256 + tid;
    const short8* k8 = (const short8*)(Y + (size_t)(b * SS + s) * NY + h * DD);
    float dot = 0.0f;
#pragma unroll
    for (int i = 0; i < 8; ++i) {
      short8 kv = k8[i];
#pragma unroll
      for (int e = 0; e < 8; ++e) dot += qf[i * 8 + e] * bf2f((unsigned short)kv[e]);
    }
    dot *= 0.125f;

    float mx = dot;
    for (int o = 32; o; o >>= 1) mx = fmaxf(mx, __shfl_xor(mx, o));
    if ((tid & 63) == 0) red[tid >> 6] = mx;
    __syncthreads();
    float M = fmaxf(fmaxf(red[0], red[1]), fmaxf(red[2], red[3]));

    float p = __expf(dot - M);
    ps[tid] = p;
    float l = p;
    for (int o = 32; o; o >>= 1) l += __shfl_xor(l, o);
    if ((tid & 63) == 0) red[4 + (tid >> 6)] = l;
    __syncthreads();
    float L = red[4] + red[5] + red[6] + red[7];

    // V-accumulate, vectorized: thread = (sl-lane = tid>>3, d-octet = tid&7)
    float a8[8] = {0.f, 0.f, 0.f, 0.f, 0.f, 0.f, 0.f, 0.f};
    const int oct = tid & 7;
#pragma unroll
    for (int it = 0; it < 8; ++it) {
      int sl = (tid >> 3) + it * 32;
      float p2 = ps[sl];
      short8 v = *(const short8*)&Y[(size_t)(b * SS + kc * 256 + sl) * NY + 1024 + h * DD + oct * 8];
#pragma unroll
      for (int e = 0; e < 8; ++e) a8[e] += p2 * bf2f((unsigned short)v[e]);
    }
#pragma unroll
    for (int e = 0; e < 8; ++e) {
      a8[e] += __shfl_xor(a8[e], 8);
      a8[e] += __shfl_xor(a8[e], 16);
      a8[e] += __shfl_xor(a8[e], 32);
    }
    if (lane < 8) {
#pragma unroll
      for (int e = 0; e < 8; ++e) pacc[wid][lane * 8 + e] = a8[e];
    }
    __syncthreads();
    if (tid < 64) {
      float a = pacc[0][tid] + pacc[1][tid] + pacc[2][tid] + pacc[3][tid];
      float* pp = part + ((size_t)(b * HH + h) * 8 + kc) * 66;
      if (tid == 0) { pp[0] = M; pp[1] = L; }
      pp[2 + tid] = a;
    }
    return;
  }

  // ===== local attention via MFMA =====
  const int s0 = blockIdx.x * QBL;
  const int rl = lane & 15, g = lane >> 4;

  for (int task = tid; task < 640; task += 256) {
    int kp = task % 80, ch = task / 80;
    int k0 = kp * 2;
    int kg0 = min(max(s0 - 16 + k0, 0), SS - 1);
    int kg1 = min(max(s0 - 16 + k0 + 1, 0), SS - 1);
    short8 a = *(const short8*)&Y[(size_t)(b * SS + kg0) * NY + 4096 + h * DD + ch * 8];
    short8 bv = *(const short8*)&Y[(size_t)(b * SS + kg1) * NY + 4096 + h * DD + ch * 8];
#pragma unroll
    for (int e = 0; e < 8; ++e) {
      unsigned int w = (unsigned int)(unsigned short)a[e] |
                       ((unsigned int)(unsigned short)bv[e] << 16);
      *(unsigned int*)&Vt[ch * 8 + e][k0] = w;
    }
  }
  __syncthreads();

  const int qb = s0 + wid * 32;
  const int kb = qb - 16;

  short8 ak[4][2];
#pragma unroll
  for (int kt = 0; kt < 4; ++kt) {
    int kg = min(max(kb + kt * 16 + rl, 0), SS - 1);
    const unsigned short* kr = &Y[(size_t)(b * SS + kg) * NY + 3072 + h * DD + g * 8];
#pragma unroll
    for (int ks = 0; ks < 2; ++ks) ak[kt][ks] = *(const short8*)(kr + ks * 32);
  }
  short8 bq[2][2];
#pragma unroll
  for (int cc = 0; cc < 2; ++cc) {
    const unsigned short* qr = &Y[(size_t)(b * SS + qb + cc * 16 + rl) * NY + 2048 + h * DD + g * 8];
#pragma unroll
    for (int ks = 0; ks < 2; ++ks) bq[cc][ks] = *(const short8*)(qr + ks * 32);
  }

  f32x4 accs[4][2] = {};
#pragma unroll
  for (int kt = 0; kt < 4; ++kt)
#pragma unroll
    for (int cc = 0; cc < 2; ++cc)
#pragma unroll
      for (int ks = 0; ks < 2; ++ks)
        accs[kt][cc] = __builtin_amdgcn_mfma_f32_16x16x32_bf16(
            ak[kt][ks], bq[cc][ks], accs[kt][cc], 0, 0, 0);

  float mrow[2] = {-3e38f, -3e38f};
#pragma unroll
  for (int kt = 0; kt < 4; ++kt)
#pragma unroll
    for (int cc = 0; cc < 2; ++cc)
#pragma unroll
      for (int r = 0; r < 4; ++r) {
        int kg = kb + kt * 16 + 4 * g + r;
        int qg = qb + cc * 16 + rl;
        bool valid = (kg >= qg - 16) && (kg <= qg + 16) && (kg >= 1) && (kg < SS);
        float v = valid ? accs[kt][cc][r] : -3e38f;
        accs[kt][cc][r] = v;
        mrow[cc] = fmaxf(mrow[cc], v);
      }
#pragma unroll
  for (int cc = 0; cc < 2; ++cc) {
    float m = mrow[cc];
    m = fmaxf(m, __shfl_xor(m, 16));
    m = fmaxf(m, __shfl_xor(m, 32));
    mrow[cc] = m;
  }

  float zrow[2] = {0.0f, 0.0f};
#pragma unroll
  for (int cc = 0; cc < 2; ++cc)
#pragma unroll
    for (int kt = 0; kt < 4; ++kt) {
      ushort4 pw;
#pragma unroll
      for (int r = 0; r < 4; ++r) {
        float p = __expf((accs[kt][cc][r] - mrow[cc]) * 0.125f);
        zrow[cc] += p;
        ((unsigned short*)&pw)[r] = f2bf(p);
      }
      *(ushort4*)&Pl[wid][cc * 16 + rl][kt * 16 + 4 * g] = pw;
    }
#pragma unroll
  for (int cc = 0; cc < 2; ++cc) {
    float z = zrow[cc];
    z += __shfl_xor(z, 16);
    z += __shfl_xor(z, 32);
    zrow[cc] = 1.0f / z;
  }

  f32x4 accp[4][2] = {};
#pragma unroll
  for (int ks = 0; ks < 2; ++ks) {
    short8 bp[2];
#pragma unroll
    for (int cc = 0; cc < 2; ++cc)
      bp[cc] = *(const short8*)&Pl[wid][cc * 16 + rl][ks * 32 + g * 8];
#pragma unroll
    for (int mt = 0; mt < 4; ++mt) {
      short8 av = *(const short8*)&Vt[mt * 16 + rl][wid * 32 + ks * 32 + g * 8];
#pragma unroll
      for (int cc = 0; cc < 2; ++cc)
        accp[mt][cc] = __builtin_amdgcn_mfma_f32_16x16x32_bf16(
            av, bp[cc], accp[mt][cc], 0, 0, 0);
    }
  }

#pragma unroll
  for (int mt = 0; mt < 4; ++mt)
#pragma unroll
    for (int cc = 0; cc < 2; ++cc) {
      int token = qb + cc * 16 + rl;
      if (token == 0) {
        *(ushort4*)&CTX[(size_t)(b * SS) * EE + h * DD + mt * 16 + 4 * g] = ushort4{0, 0, 0, 0};
        continue;
      }
      ushort4 o;
#pragma unroll
      for (int r = 0; r < 4; ++r)
        ((unsigned short*)&o)[r] = f2bf(accp[mt][cc][r] * zrow[cc]);
      *(ushort4*)&CTX[(size_t)(b * SS + token) * EE + h * DD + mt * 16 + 4 * g] = o;
    }
}

extern "C" void kernel_launch(void* const* d_in, const int* in_sizes, int n_in,
                              void* d_out, int out_size, void* d_ws, size_t ws_size,
                              hipStream_t stream) {
  const float* hs        = (const float*)d_in[0];
  const float* in_w_cls  = (const float*)d_in[1];
  const float* in_b_cls  = (const float*)d_in[2];
  const float* out_w_cls = (const float*)d_in[3];
  const float* out_b_cls = (const float*)d_in[4];
  const float* in_w_loc  = (const float*)d_in[5];
  const float* in_b_loc  = (const float*)d_in[6];
  const float* out_w_loc = (const float*)d_in[7];
  const float* out_b_loc = (const float*)d_in[8];
  float* out = (float*)d_out;

  const int M = BB * SS;  // 4096
  char* ws = (char*)d_ws;
  size_t off = 0;
  auto alloc = [&](size_t bytes) { char* p = ws + off; off += (bytes + 255) & ~(size_t)255; return p; };
  unsigned short* Xbf  = (unsigned short*)alloc((size_t)M * EE * 2);
  unsigned short* W    = (unsigned short*)alloc((size_t)NY * EE * 2);
  unsigned short* Wout = (unsigned short*)alloc((size_t)EE * EE * 2);
  unsigned short* Yb   = (unsigned short*)alloc((size_t)M * NY * 2);
  unsigned short* CTX  = (unsigned short*)alloc((size_t)M * EE * 2);
  float* qcls = (float*)alloc(2 * EE * 4);
  float* part = (float*)alloc((size_t)BB * HH * 8 * 66 * 4);

  // 1) fused casts + q_cls GEMV
  cast_all<<<10752, 256, 0, stream>>>(
      hs, Xbf,
      in_w_cls + (size_t)EE * EE, W,
      in_w_loc, W + (size_t)2048 * EE,
      out_w_loc, Wout,
      in_w_cls, in_b_cls, qcls);

  // 2) merged projection GEMM (r15-proven A-frag pipelined, 256x320, 256 blocks)
  gemm8p<<<256, 512, 0, stream>>>(Xbf, W, in_b_cls, in_b_loc, Yb);

  // 3) fused attention (local MFMA + cls partials, vectorized V-accumulate)
  attn_fused<<<dim3(24, HH, BB), 256, 0, stream>>>(qcls, Yb, part, CTX);

  // 4) out-proj GEMM + cls rows (one launch; GEMM skips rows 0/2048)
  gemm_out<<<768, 256, 0, stream>>>(CTX, Wout, out_b_loc, out,
                                    part, out_w_cls, out_b_cls);
}

// Round 18
// 102.616 us; speedup vs baseline: 1.4599x; 1.0102x over previous
//
#include <hip/hip_runtime.h>

// Problem constants: B=2, S=2048, E=1024, H=16, D=64, WIN=16
#define BB 2
#define SS 2048
#define EE 1024
#define HH 16
#define DD 64
#define NY 5120   // merged projection output cols: [Kcls|Vcls|Qloc|Kloc|Vloc]

typedef __attribute__((ext_vector_type(8))) short short8;
typedef __attribute__((ext_vector_type(4))) float f32x4;

__device__ __forceinline__ float bf2f(unsigned short u) {
  union { unsigned int i; float f; } v; v.i = ((unsigned int)u) << 16; return v.f;
}
__device__ __forceinline__ unsigned short f2bf(float f) {
  unsigned int u = __float_as_uint(f);
  u += 0x7fff + ((u >> 16) & 1);   // RNE
  return (unsigned short)(u >> 16);
}
__device__ __forceinline__ void gload_lds16(const void* g, void* l) {
  __builtin_amdgcn_global_load_lds(
      (const __attribute__((address_space(1))) void*)g,
      (__attribute__((address_space(3))) void*)l, 16, 0, 0);
}

// ---------------- fused f32->bf16 casts + q_cls GEMV (one launch) ----------------
__global__ void cast_all(const float* __restrict__ s0, unsigned short* __restrict__ d0,
                         const float* __restrict__ s1, unsigned short* __restrict__ d1,
                         const float* __restrict__ s2, unsigned short* __restrict__ d2,
                         const float* __restrict__ s3, unsigned short* __restrict__ d3,
                         const float* __restrict__ in_w_cls,
                         const float* __restrict__ in_b_cls,
                         float* __restrict__ qcls) {
  int b = blockIdx.x;
  if (b >= 10240) {   // q_cls GEMV: 512 blocks x 4 rows
    int gw = (b - 10240) * 4 + (threadIdx.x >> 6);
    int lane = threadIdx.x & 63;
    int bb = gw >> 10, n = gw & 1023;
    const float* x = s0 + (size_t)bb * SS * EE;
    const float* w = in_w_cls + (size_t)n * EE;
    float s = 0.0f;
    for (int k = lane; k < EE; k += 64) s += x[k] * w[k];
    for (int o = 32; o; o >>= 1) s += __shfl_xor(s, o);
    if (lane == 0) qcls[bb * EE + n] = s + in_b_cls[n];
    return;
  }
  const float* s; unsigned short* d; int idx;
  if (b < 4096)      { s = s0; d = d0; idx = b; }
  else if (b < 6144) { s = s1; d = d1; idx = b - 4096; }
  else if (b < 9216) { s = s2; d = d2; idx = b - 6144; }
  else               { s = s3; d = d3; idx = b - 9216; }
  int i = (idx * 256 + threadIdx.x) * 4;
  float4 v = *reinterpret_cast<const float4*>(s + i);
  ushort4 o;
  o.x = f2bf(v.x); o.y = f2bf(v.y); o.z = f2bf(v.z); o.w = f2bf(v.w);
  *reinterpret_cast<ushort4*>(d + i) = o;
}

// ================= 8-phase 256x320 projection GEMM — A-frag pipelined (r15) =======
#define SBAR __builtin_amdgcn_sched_barrier(0)
#define RAWBAR do { SBAR; __builtin_amdgcn_s_barrier(); SBAR; } while (0)
#define WAITVM0 do { asm volatile("s_waitcnt vmcnt(0)" ::: "memory"); SBAR; } while (0)
#define LGKM0 do { asm volatile("s_waitcnt lgkmcnt(0)" ::: "memory"); SBAR; } while (0)
#define LGKMW(n) do { asm volatile("s_waitcnt lgkmcnt(" #n ")" ::: "memory"); SBAR; } while (0)

#define MFMA20(FAX, MH)                                                              \
  _Pragma("unroll")                                                                  \
  for (int m = 0; m < 4; ++m)                                                        \
    _Pragma("unroll")                                                                \
    for (int n = 0; n < 5; ++n)                                                      \
      acc[(MH) * 4 + m][n] = __builtin_amdgcn_mfma_f32_16x16x32_bf16(                \
          FAX[m], bfr[n], acc[(MH) * 4 + m][n], 0, 0, 0);

__global__ __launch_bounds__(512)
void gemm8p(const unsigned short* __restrict__ Ag,   // [4096][1024]
            const unsigned short* __restrict__ Bg,   // [5120][1024]
            const float* __restrict__ bcls,
            const float* __restrict__ bloc,
            unsigned short* __restrict__ Yout) {     // [4096][5120]
  __shared__ unsigned short As2[2][256][64];   // 64 KiB
  __shared__ unsigned short Bs2[2][320][64];   // 80 KiB
  char* ldsA = (char*)As2;
  char* ldsB = (char*)Bs2;

  const int tid = threadIdx.x;
  const int wid = tid >> 6;
  const int lane = tid & 63;
  const int wm = wid >> 2;     // 0..1 -> 128-row slice
  const int wn = wid & 3;      // 0..3 -> 80-col slice
  const int rl = lane & 15;
  const int g4 = lane >> 4;

  int bid = blockIdx.x;
  bid = (bid & 7) * 32 + (bid >> 3);     // XCD swizzle, bijective (256 = 8*32)
  const int tileM = (bid & 15) * 256;
  const int tileN = (bid >> 4) * 320;

  f32x4 acc[8][5] = {};
  short8 FA0[4], FA1[4], bfr[5];

  auto SA = [&](int c, int kk, int i) {
    int flat = i * 8192 + tid * 16;
    int row = flat >> 7;
    int colb = (flat & 127) ^ ((row & 7) << 4);
    gload_lds16(Ag + (size_t)(tileM + row) * 1024 + kk + (colb >> 1),
                ldsA + c * 32768 + i * 8192 + wid * 1024);
  };
  auto SB = [&](int c, int kk, int j) {
    int flat = j * 8192 + tid * 16;
    int row = flat >> 7;
    int colb = (flat & 127) ^ ((row & 7) << 4);
    gload_lds16(Bg + (size_t)(tileN + row) * 1024 + kk + (colb >> 1),
                ldsB + c * 40960 + j * 8192 + wid * 1024);
  };
  auto DSA = [&](int c, int mh, int kh, short8* dst) {
#pragma unroll
    for (int m = 0; m < 4; ++m) {
      int row = wm * 128 + mh * 64 + m * 16 + rl;
      const char* base = ldsA + c * 32768 + row * 128;
      dst[m] = *(const short8*)(base + ((kh * 64 + g4 * 16) ^ ((row & 7) << 4)));
    }
  };
  auto DSB = [&](int c, int kh) {
#pragma unroll
    for (int n = 0; n < 5; ++n) {
      int row = wn * 80 + n * 16 + rl;
      const char* base = ldsB + c * 40960 + row * 128;
      bfr[n] = *(const short8*)(base + ((kh * 64 + g4 * 16) ^ ((row & 7) << 4)));
    }
  };

  // prologue: tile 0 -> buf0, then pre-read P0 frags (9 reads in flight)
  SA(0, 0, 0); SA(0, 0, 1); SA(0, 0, 2); SA(0, 0, 3);
  SB(0, 0, 0); SB(0, 0, 1); SB(0, 0, 2); SB(0, 0, 3); SB(0, 0, 4);
  WAITVM0;
  RAWBAR;
  DSB(0, 0); DSA(0, 0, 0, FA0);

#pragma unroll 1
  for (int t = 0; t < 16; ++t) {
    const int c = t & 1;
    const int kk = (t + 1) * 64;
    const bool st = (t < 15);
    // P0 (mh0,kh0): pre-read P1's A-frags
    DSA(c, 1, 0, FA1);
    if (st) { SA(c ^ 1, kk, 0); SA(c ^ 1, kk, 1); }
    RAWBAR; LGKMW(4);
    __builtin_amdgcn_s_setprio(1); MFMA20(FA0, 0); __builtin_amdgcn_s_setprio(0);
    RAWBAR;
    // P1 (mh1,kh0): pre-read P2's A-frags
    DSA(c, 0, 1, FA0);
    if (st) { SA(c ^ 1, kk, 2); SA(c ^ 1, kk, 3); }
    RAWBAR; LGKMW(4);
    __builtin_amdgcn_s_setprio(1); MFMA20(FA1, 1); __builtin_amdgcn_s_setprio(0);
    RAWBAR;
    // P2 (mh0,kh1): B kh-transition + P3's A-frags
    DSB(c, 1); DSA(c, 1, 1, FA1);
    if (st) { SB(c ^ 1, kk, 0); SB(c ^ 1, kk, 1); SB(c ^ 1, kk, 2); }
    RAWBAR; LGKM0;
    __builtin_amdgcn_s_setprio(1); MFMA20(FA0, 0); __builtin_amdgcn_s_setprio(0);
    RAWBAR;
    // P3 (mh1,kh1): all frags resident
    if (st) { SB(c ^ 1, kk, 3); SB(c ^ 1, kk, 4); }
    RAWBAR;
    __builtin_amdgcn_s_setprio(1); MFMA20(FA1, 1); __builtin_amdgcn_s_setprio(0);
    if (st) WAITVM0;    // full drain: publishes ALL waves' staging (no race)
    RAWBAR;
    if (st) { DSB(c ^ 1, 0); DSA(c ^ 1, 0, 0, FA0); }
  }

  // epilogue
#pragma unroll
  for (int m = 0; m < 8; ++m)
#pragma unroll
    for (int n = 0; n < 5; ++n) {
      int gc = tileN + wn * 80 + n * 16 + rl;
      float bv = (gc < 2048) ? bcls[1024 + gc] : bloc[gc - 2048];
#pragma unroll
      for (int r = 0; r < 4; ++r) {
        int gr = tileM + wm * 128 + m * 16 + g4 * 4 + r;
        Yout[(size_t)gr * NY + gc] = f2bf(acc[m][n][r] + bv);
      }
    }
}

// ---------------- out-proj GEMM + cls-row GEMV fused (one launch) ----------------
__global__ __launch_bounds__(256, 4)
void gemm_out(const unsigned short* __restrict__ A,     // CTX [4096][1024]
              const unsigned short* __restrict__ B,     // Wout [1024][1024]
              const float* __restrict__ bias0,          // out_b_loc
              float* __restrict__ C,                    // out [4096][1024]
              const float* __restrict__ part,           // cls partials
              const float* __restrict__ Wc,             // out_w_cls
              const float* __restrict__ bc) {           // out_b_cls
  __shared__ unsigned short As[2][128 * 32];
  __shared__ unsigned short Bs[2][128 * 32];
  __shared__ float ctx[EE];
  __shared__ float u[HH][8];

  const int tid = threadIdx.x;

  if (blockIdx.x >= 256) {
    const int cid = blockIdx.x - 256;        // 0..511
    const int b = cid >> 8;
    const float* pb = part + (size_t)b * HH * 8 * 66;
    if (tid < HH) {
      const float* pp = pb + tid * 8 * 66;
      float M = -1e30f;
#pragma unroll
      for (int i = 0; i < 8; ++i) M = fmaxf(M, pp[i * 66]);
      float Z = 0.0f, w[8];
#pragma unroll
      for (int i = 0; i < 8; ++i) { w[i] = __expf(pp[i * 66] - M); Z += w[i] * pp[i * 66 + 1]; }
#pragma unroll
      for (int i = 0; i < 8; ++i) u[tid][i] = w[i] / Z;
    }
    __syncthreads();
    for (int k = tid; k < EE; k += 256) {
      int hh = k >> 6, d = k & 63;
      const float* pp = pb + hh * 8 * 66 + 2 + d;
      float a = 0.0f;
#pragma unroll
      for (int i = 0; i < 8; ++i) a += u[hh][i] * pp[i * 66];
      ctx[k] = a;
    }
    __syncthreads();
    int n = (cid & 255) * 4 + (tid >> 6);
    int lane = tid & 63;
    const float* w = Wc + (size_t)n * EE;
    float s = 0.0f;
    for (int k = lane; k < EE; k += 64) s += ctx[k] * w[k];
    for (int o = 32; o; o >>= 1) s += __shfl_xor(s, o);
    if (lane == 0) C[(size_t)b * SS * EE + n] = s + bc[n];
    return;
  }

  const int wid = tid >> 6;
  const int lane = tid & 63;
  int bid = blockIdx.x;
  bid = (bid & 7) * 32 + (bid >> 3);       // XCD swizzle over 256
  const int tileM = (bid % 32) * 128;
  const int tileN = (bid / 32) * 128;

  const int wm = (wid >> 1) * 64;
  const int wn = (wid & 1) * 64;
  const int rl = lane & 15;
  const int kc = (lane >> 4) * 8;

  f32x4 acc[4][4] = {};

  const int srow = tid >> 2;
  const int scol = (tid & 3) * 8;
  const unsigned short* gA = A + (size_t)(tileM + srow) * EE + scol;
  const unsigned short* gB = B + (size_t)(tileN + srow) * EE + scol;
  char* lA = (char*)As + wid * 1024;
  char* lB = (char*)Bs + wid * 1024;

  auto STAGE = [&](int buf, int k0) {
    gload_lds16(gA + k0, lA + buf * 8192);
    gload_lds16(gA + (size_t)64 * EE + k0, lA + buf * 8192 + 4096);
    gload_lds16(gB + k0, lB + buf * 8192);
    gload_lds16(gB + (size_t)64 * EE + k0, lB + buf * 8192 + 4096);
  };
  auto COMPUTE = [&](int buf) {
    const unsigned short* as = As[buf];
    const unsigned short* bs = Bs[buf];
    short8 af[4], bfg[4];
#pragma unroll
    for (int mi = 0; mi < 4; ++mi)
      af[mi] = *reinterpret_cast<const short8*>(&as[(wm + mi * 16 + rl) * 32 + kc]);
#pragma unroll
    for (int ni = 0; ni < 4; ++ni)
      bfg[ni] = *reinterpret_cast<const short8*>(&bs[(wn + ni * 16 + rl) * 32 + kc]);
#pragma unroll
    for (int mi = 0; mi < 4; ++mi)
#pragma unroll
      for (int ni = 0; ni < 4; ++ni)
        acc[mi][ni] = __builtin_amdgcn_mfma_f32_16x16x32_bf16(
            af[mi], bfg[ni], acc[mi][ni], 0, 0, 0);
  };

  STAGE(0, 0);
  asm volatile("s_waitcnt vmcnt(0)" ::: "memory");
  __syncthreads();
  int cur = 0;
  for (int k0 = 32; k0 < EE; k0 += 32) {
    STAGE(cur ^ 1, k0);
    COMPUTE(cur);
    asm volatile("s_waitcnt vmcnt(0)" ::: "memory");
    __syncthreads();
    cur ^= 1;
  }
  COMPUTE(cur);

  const int crow0 = (lane >> 4) * 4;
  const int ccol = lane & 15;
#pragma unroll
  for (int mi = 0; mi < 4; ++mi)
#pragma unroll
    for (int ni = 0; ni < 4; ++ni) {
      int gc = tileN + wn + ni * 16 + ccol;
      float bv = bias0[gc];
#pragma unroll
      for (int r = 0; r < 4; ++r) {
        int gr = tileM + wm + mi * 16 + crow0 + r;
        if (gr & 2047)   // rows 0 and 2048 belong to the cls blocks
          C[(size_t)gr * EE + gc] = acc[mi][ni][r] + bv;
      }
    }
}

// ---------------- fused attention: local (x<16) + global partials (x>=16) ----------------
#define QBL 128
#define VT_PAD 168
#define P_PAD 72
__global__ __launch_bounds__(256, 2)
void attn_fused(const float* __restrict__ qcls,
                const unsigned short* __restrict__ Y,
                float* __restrict__ part,
                unsigned short* __restrict__ CTX) {
  const int h = blockIdx.y, b = blockIdx.z;
  const int tid = threadIdx.x, wid = tid >> 6, lane = tid & 63;

  __shared__ unsigned short Vt[64][VT_PAD];
  __shared__ unsigned short Pl[4][32][P_PAD];
  __shared__ float qf[64];
  __shared__ float ps[256];
  __shared__ float red[8];
  __shared__ float pacc[4][64];

  if (blockIdx.x >= 16) {
    // ===== global (cls) attention partial, key-chunk kc =====
    const int kc = blockIdx.x - 16;
    if (tid < 64) qf[tid] = qcls[b * EE + h * DD + tid];
    __syncthreads();

    // QK dot, coalesced: thread = (key-group sl = tid>>3, d-octet = tid&7);
    // 8 consecutive lanes read 8 consecutive 16B chunks of one K row (128B).
    const int sl = tid >> 3, oct = tid & 7;
    float d8[8];
#pragma unroll
    for (int it = 0; it < 8; ++it) {
      int key = sl + it * 32;
      short8 kv = *(const short8*)&Y[(size_t)(b * SS + kc * 256 + key) * NY + h * DD + oct * 8];
      float d = 0.0f;
#pragma unroll
      for (int e = 0; e < 8; ++e) d += qf[oct * 8 + e] * bf2f((unsigned short)kv[e]);
      d8[it] = d;
    }
#pragma unroll
    for (int it = 0; it < 8; ++it) {
      d8[it] += __shfl_xor(d8[it], 1);
      d8[it] += __shfl_xor(d8[it], 2);
      d8[it] += __shfl_xor(d8[it], 4);
    }
    if (oct == 0) {
#pragma unroll
      for (int it = 0; it < 8; ++it) ps[sl + it * 32] = d8[it] * 0.125f;
    }
    __syncthreads();

    float dot = ps[tid];
    float mx = dot;
    for (int o = 32; o; o >>= 1) mx = fmaxf(mx, __shfl_xor(mx, o));
    if ((tid & 63) == 0) red[tid >> 6] = mx;
    __syncthreads();
    float M = fmaxf(fmaxf(red[0], red[1]), fmaxf(red[2], red[3]));

    float p = __expf(dot - M);
    ps[tid] = p;
    float l = p;
    for (int o = 32; o; o >>= 1) l += __shfl_xor(l, o);
    if ((tid & 63) == 0) red[4 + (tid >> 6)] = l;
    __syncthreads();
    float L = red[4] + red[5] + red[6] + red[7];

    // V-accumulate, vectorized (r17-proven): thread = (sl-lane = tid>>3, d-octet)
    float a8[8] = {0.f, 0.f, 0.f, 0.f, 0.f, 0.f, 0.f, 0.f};
#pragma unroll
    for (int it = 0; it < 8; ++it) {
      int slv = (tid >> 3) + it * 32;
      float p2 = ps[slv];
      short8 v = *(const short8*)&Y[(size_t)(b * SS + kc * 256 + slv) * NY + 1024 + h * DD + oct * 8];
#pragma unroll
      for (int e = 0; e < 8; ++e) a8[e] += p2 * bf2f((unsigned short)v[e]);
    }
#pragma unroll
    for (int e = 0; e < 8; ++e) {
      a8[e] += __shfl_xor(a8[e], 8);
      a8[e] += __shfl_xor(a8[e], 16);
      a8[e] += __shfl_xor(a8[e], 32);
    }
    if (lane < 8) {
#pragma unroll
      for (int e = 0; e < 8; ++e) pacc[wid][lane * 8 + e] = a8[e];
    }
    __syncthreads();
    if (tid < 64) {
      float a = pacc[0][tid] + pacc[1][tid] + pacc[2][tid] + pacc[3][tid];
      float* pp = part + ((size_t)(b * HH + h) * 8 + kc) * 66;
      if (tid == 0) { pp[0] = M; pp[1] = L; }
      pp[2 + tid] = a;
    }
    return;
  }

  // ===== local attention via MFMA =====
  const int s0 = blockIdx.x * QBL;
  const int rl = lane & 15, g = lane >> 4;

  // stage V^T coalesced: task = (row 0..159, oct 0..7); 8 lanes per row (128B)
  for (int task = tid; task < 1280; task += 256) {
    int row = task >> 3, oc = task & 7;
    int kg = min(max(s0 - 16 + row, 0), SS - 1);
    short8 v = *(const short8*)&Y[(size_t)(b * SS + kg) * NY + 4096 + h * DD + oc * 8];
#pragma unroll
    for (int e = 0; e < 8; ++e) Vt[oc * 8 + e][row] = (unsigned short)v[e];
  }
  __syncthreads();

  const int qb = s0 + wid * 32;
  const int kb = qb - 16;

  short8 ak[4][2];
#pragma unroll
  for (int kt = 0; kt < 4; ++kt) {
    int kg = min(max(kb + kt * 16 + rl, 0), SS - 1);
    const unsigned short* kr = &Y[(size_t)(b * SS + kg) * NY + 3072 + h * DD + g * 8];
#pragma unroll
    for (int ks = 0; ks < 2; ++ks) ak[kt][ks] = *(const short8*)(kr + ks * 32);
  }
  short8 bq[2][2];
#pragma unroll
  for (int cc = 0; cc < 2; ++cc) {
    const unsigned short* qr = &Y[(size_t)(b * SS + qb + cc * 16 + rl) * NY + 2048 + h * DD + g * 8];
#pragma unroll
    for (int ks = 0; ks < 2; ++ks) bq[cc][ks] = *(const short8*)(qr + ks * 32);
  }

  f32x4 accs[4][2] = {};
#pragma unroll
  for (int kt = 0; kt < 4; ++kt)
#pragma unroll
    for (int cc = 0; cc < 2; ++cc)
#pragma unroll
      for (int ks = 0; ks < 2; ++ks)
        accs[kt][cc] = __builtin_amdgcn_mfma_f32_16x16x32_bf16(
            ak[kt][ks], bq[cc][ks], accs[kt][cc], 0, 0, 0);

  float mrow[2] = {-3e38f, -3e38f};
#pragma unroll
  for (int kt = 0; kt < 4; ++kt)
#pragma unroll
    for (int cc = 0; cc < 2; ++cc)
#pragma unroll
      for (int r = 0; r < 4; ++r) {
        int kg = kb + kt * 16 + 4 * g + r;
        int qg = qb + cc * 16 + rl;
        bool valid = (kg >= qg - 16) && (kg <= qg + 16) && (kg >= 1) && (kg < SS);
        float v = valid ? accs[kt][cc][r] : -3e38f;
        accs[kt][cc][r] = v;
        mrow[cc] = fmaxf(mrow[cc], v);
      }
#pragma unroll
  for (int cc = 0; cc < 2; ++cc) {
    float m = mrow[cc];
    m = fmaxf(m, __shfl_xor(m, 16));
    m = fmaxf(m, __shfl_xor(m, 32));
    mrow[cc] = m;
  }

  float zrow[2] = {0.0f, 0.0f};
#pragma unroll
  for (int cc = 0; cc < 2; ++cc)
#pragma unroll
    for (int kt = 0; kt < 4; ++kt) {
      ushort4 pw;
#pragma unroll
      for (int r = 0; r < 4; ++r) {
        float p = __expf((accs[kt][cc][r] - mrow[cc]) * 0.125f);
        zrow[cc] += p;
        ((unsigned short*)&pw)[r] = f2bf(p);
      }
      *(ushort4*)&Pl[wid][cc * 16 + rl][kt * 16 + 4 * g] = pw;
    }
#pragma unroll
  for (int cc = 0; cc < 2; ++cc) {
    float z = zrow[cc];
    z += __shfl_xor(z, 16);
    z += __shfl_xor(z, 32);
    zrow[cc] = 1.0f / z;
  }

  f32x4 accp[4][2] = {};
#pragma unroll
  for (int ks = 0; ks < 2; ++ks) {
    short8 bp[2];
#pragma unroll
    for (int cc = 0; cc < 2; ++cc)
      bp[cc] = *(const short8*)&Pl[wid][cc * 16 + rl][ks * 32 + g * 8];
#pragma unroll
    for (int mt = 0; mt < 4; ++mt) {
      short8 av = *(const short8*)&Vt[mt * 16 + rl][wid * 32 + ks * 32 + g * 8];
#pragma unroll
      for (int cc = 0; cc < 2; ++cc)
        accp[mt][cc] = __builtin_amdgcn_mfma_f32_16x16x32_bf16(
            av, bp[cc], accp[mt][cc], 0, 0, 0);
    }
  }

#pragma unroll
  for (int mt = 0; mt < 4; ++mt)
#pragma unroll
    for (int cc = 0; cc < 2; ++cc) {
      int token = qb + cc * 16 + rl;
      if (token == 0) {
        *(ushort4*)&CTX[(size_t)(b * SS) * EE + h * DD + mt * 16 + 4 * g] = ushort4{0, 0, 0, 0};
        continue;
      }
      ushort4 o;
#pragma unroll
      for (int r = 0; r < 4; ++r)
        ((unsigned short*)&o)[r] = f2bf(accp[mt][cc][r] * zrow[cc]);
      *(ushort4*)&CTX[(size_t)(b * SS + token) * EE + h * DD + mt * 16 + 4 * g] = o;
    }
}

extern "C" void kernel_launch(void* const* d_in, const int* in_sizes, int n_in,
                              void* d_out, int out_size, void* d_ws, size_t ws_size,
                              hipStream_t stream) {
  const float* hs        = (const float*)d_in[0];
  const float* in_w_cls  = (const float*)d_in[1];
  const float* in_b_cls  = (const float*)d_in[2];
  const float* out_w_cls = (const float*)d_in[3];
  const float* out_b_cls = (const float*)d_in[4];
  const float* in_w_loc  = (const float*)d_in[5];
  const float* in_b_loc  = (const float*)d_in[6];
  const float* out_w_loc = (const float*)d_in[7];
  const float* out_b_loc = (const float*)d_in[8];
  float* out = (float*)d_out;

  const int M = BB * SS;  // 4096
  char* ws = (char*)d_ws;
  size_t off = 0;
  auto alloc = [&](size_t bytes) { char* p = ws + off; off += (bytes + 255) & ~(size_t)255; return p; };
  unsigned short* Xbf  = (unsigned short*)alloc((size_t)M * EE * 2);
  unsigned short* W    = (unsigned short*)alloc((size_t)NY * EE * 2);
  unsigned short* Wout = (unsigned short*)alloc((size_t)EE * EE * 2);
  unsigned short* Yb   = (unsigned short*)alloc((size_t)M * NY * 2);
  unsigned short* CTX  = (unsigned short*)alloc((size_t)M * EE * 2);
  float* qcls = (float*)alloc(2 * EE * 4);
  float* part = (float*)alloc((size_t)BB * HH * 8 * 66 * 4);

  // 1) fused casts + q_cls GEMV
  cast_all<<<10752, 256, 0, stream>>>(
      hs, Xbf,
      in_w_cls + (size_t)EE * EE, W,
      in_w_loc, W + (size_t)2048 * EE,
      out_w_loc, Wout,
      in_w_cls, in_b_cls, qcls);

  // 2) merged projection GEMM (r15-proven A-frag pipelined, 256x320, 256 blocks)
  gemm8p<<<256, 512, 0, stream>>>(Xbf, W, in_b_cls, in_b_loc, Yb);

  // 3) fused attention (coalesced QK dot + Vt staging + V-accumulate)
  attn_fused<<<dim3(24, HH, BB), 256, 0, stream>>>(qcls, Yb, part, CTX);

  // 4) out-proj GEMM + cls rows (one launch; GEMM skips rows 0/2048)
  gemm_out<<<768, 256, 0, stream>>>(CTX, Wout, out_b_loc, out,
                                    part, out_w_cls, out_b_cls);
}

// Round 19
// 100.516 us; speedup vs baseline: 1.4904x; 1.0209x over previous
//
#include <hip/hip_runtime.h>

// Problem constants: B=2, S=2048, E=1024, H=16, D=64, WIN=16
#define BB 2
#define SS 2048
#define EE 1024
#define HH 16
#define DD 64
#define NY 5120   // merged projection output cols: [Kcls|Vcls|Qloc|Kloc|Vloc]

typedef __attribute__((ext_vector_type(8))) short short8;
typedef __attribute__((ext_vector_type(4))) float f32x4;

__device__ __forceinline__ float bf2f(unsigned short u) {
  union { unsigned int i; float f; } v; v.i = ((unsigned int)u) << 16; return v.f;
}
__device__ __forceinline__ unsigned short f2bf(float f) {
  unsigned int u = __float_as_uint(f);
  u += 0x7fff + ((u >> 16) & 1);   // RNE
  return (unsigned short)(u >> 16);
}
__device__ __forceinline__ void gload_lds16(const void* g, void* l) {
  __builtin_amdgcn_global_load_lds(
      (const __attribute__((address_space(1))) void*)g,
      (__attribute__((address_space(3))) void*)l, 16, 0, 0);
}

// ---------------- fused f32->bf16 casts + q_cls GEMV (one launch) ----------------
__global__ void cast_all(const float* __restrict__ s0, unsigned short* __restrict__ d0,
                         const float* __restrict__ s1, unsigned short* __restrict__ d1,
                         const float* __restrict__ s2, unsigned short* __restrict__ d2,
                         const float* __restrict__ s3, unsigned short* __restrict__ d3,
                         const float* __restrict__ in_w_cls,
                         const float* __restrict__ in_b_cls,
                         float* __restrict__ qcls) {
  int b = blockIdx.x;
  if (b >= 10240) {   // q_cls GEMV: 512 blocks x 4 rows
    int gw = (b - 10240) * 4 + (threadIdx.x >> 6);
    int lane = threadIdx.x & 63;
    int bb = gw >> 10, n = gw & 1023;
    const float* x = s0 + (size_t)bb * SS * EE;
    const float* w = in_w_cls + (size_t)n * EE;
    float s = 0.0f;
    for (int k = lane; k < EE; k += 64) s += x[k] * w[k];
    for (int o = 32; o; o >>= 1) s += __shfl_xor(s, o);
    if (lane == 0) qcls[bb * EE + n] = s + in_b_cls[n];
    return;
  }
  const float* s; unsigned short* d; int idx;
  if (b < 4096)      { s = s0; d = d0; idx = b; }
  else if (b < 6144) { s = s1; d = d1; idx = b - 4096; }
  else if (b < 9216) { s = s2; d = d2; idx = b - 6144; }
  else               { s = s3; d = d3; idx = b - 9216; }
  int i = (idx * 256 + threadIdx.x) * 4;
  float4 v = *reinterpret_cast<const float4*>(s + i);
  ushort4 o;
  o.x = f2bf(v.x); o.y = f2bf(v.y); o.z = f2bf(v.z); o.w = f2bf(v.w);
  *reinterpret_cast<ushort4*>(d + i) = o;
}

// ================= 8-phase 256x320 projection GEMM — A-frag pipelined (r15) =======
#define SBAR __builtin_amdgcn_sched_barrier(0)
#define RAWBAR do { SBAR; __builtin_amdgcn_s_barrier(); SBAR; } while (0)
#define WAITVM0 do { asm volatile("s_waitcnt vmcnt(0)" ::: "memory"); SBAR; } while (0)
#define LGKM0 do { asm volatile("s_waitcnt lgkmcnt(0)" ::: "memory"); SBAR; } while (0)
#define LGKMW(n) do { asm volatile("s_waitcnt lgkmcnt(" #n ")" ::: "memory"); SBAR; } while (0)

#define MFMA20(FAX, MH)                                                              \
  _Pragma("unroll")                                                                  \
  for (int m = 0; m < 4; ++m)                                                        \
    _Pragma("unroll")                                                                \
    for (int n = 0; n < 5; ++n)                                                      \
      acc[(MH) * 4 + m][n] = __builtin_amdgcn_mfma_f32_16x16x32_bf16(                \
          FAX[m], bfr[n], acc[(MH) * 4 + m][n], 0, 0, 0);

__global__ __launch_bounds__(512)
void gemm8p(const unsigned short* __restrict__ Ag,   // [4096][1024]
            const unsigned short* __restrict__ Bg,   // [5120][1024]
            const float* __restrict__ bcls,
            const float* __restrict__ bloc,
            unsigned short* __restrict__ Yout) {     // [4096][5120]
  __shared__ unsigned short As2[2][256][64];   // 64 KiB
  __shared__ unsigned short Bs2[2][320][64];   // 80 KiB
  char* ldsA = (char*)As2;
  char* ldsB = (char*)Bs2;

  const int tid = threadIdx.x;
  const int wid = tid >> 6;
  const int lane = tid & 63;
  const int wm = wid >> 2;     // 0..1 -> 128-row slice
  const int wn = wid & 3;      // 0..3 -> 80-col slice
  const int rl = lane & 15;
  const int g4 = lane >> 4;

  int bid = blockIdx.x;
  bid = (bid & 7) * 32 + (bid >> 3);     // XCD swizzle, bijective (256 = 8*32)
  const int tileM = (bid & 15) * 256;
  const int tileN = (bid >> 4) * 320;

  f32x4 acc[8][5] = {};
  short8 FA0[4], FA1[4], bfr[5];

  auto SA = [&](int c, int kk, int i) {
    int flat = i * 8192 + tid * 16;
    int row = flat >> 7;
    int colb = (flat & 127) ^ ((row & 7) << 4);
    gload_lds16(Ag + (size_t)(tileM + row) * 1024 + kk + (colb >> 1),
                ldsA + c * 32768 + i * 8192 + wid * 1024);
  };
  auto SB = [&](int c, int kk, int j) {
    int flat = j * 8192 + tid * 16;
    int row = flat >> 7;
    int colb = (flat & 127) ^ ((row & 7) << 4);
    gload_lds16(Bg + (size_t)(tileN + row) * 1024 + kk + (colb >> 1),
                ldsB + c * 40960 + j * 8192 + wid * 1024);
  };
  auto DSA = [&](int c, int mh, int kh, short8* dst) {
#pragma unroll
    for (int m = 0; m < 4; ++m) {
      int row = wm * 128 + mh * 64 + m * 16 + rl;
      const char* base = ldsA + c * 32768 + row * 128;
      dst[m] = *(const short8*)(base + ((kh * 64 + g4 * 16) ^ ((row & 7) << 4)));
    }
  };
  auto DSB = [&](int c, int kh) {
#pragma unroll
    for (int n = 0; n < 5; ++n) {
      int row = wn * 80 + n * 16 + rl;
      const char* base = ldsB + c * 40960 + row * 128;
      bfr[n] = *(const short8*)(base + ((kh * 64 + g4 * 16) ^ ((row & 7) << 4)));
    }
  };

  // prologue: tile 0 -> buf0, then pre-read P0 frags (9 reads in flight)
  SA(0, 0, 0); SA(0, 0, 1); SA(0, 0, 2); SA(0, 0, 3);
  SB(0, 0, 0); SB(0, 0, 1); SB(0, 0, 2); SB(0, 0, 3); SB(0, 0, 4);
  WAITVM0;
  RAWBAR;
  DSB(0, 0); DSA(0, 0, 0, FA0);

#pragma unroll 1
  for (int t = 0; t < 16; ++t) {
    const int c = t & 1;
    const int kk = (t + 1) * 64;
    const bool st = (t < 15);
    // P0 (mh0,kh0): pre-read P1's A-frags
    DSA(c, 1, 0, FA1);
    if (st) { SA(c ^ 1, kk, 0); SA(c ^ 1, kk, 1); }
    RAWBAR; LGKMW(4);
    __builtin_amdgcn_s_setprio(1); MFMA20(FA0, 0); __builtin_amdgcn_s_setprio(0);
    RAWBAR;
    // P1 (mh1,kh0): pre-read P2's A-frags
    DSA(c, 0, 1, FA0);
    if (st) { SA(c ^ 1, kk, 2); SA(c ^ 1, kk, 3); }
    RAWBAR; LGKMW(4);
    __builtin_amdgcn_s_setprio(1); MFMA20(FA1, 1); __builtin_amdgcn_s_setprio(0);
    RAWBAR;
    // P2 (mh0,kh1): B kh-transition + P3's A-frags
    DSB(c, 1); DSA(c, 1, 1, FA1);
    if (st) { SB(c ^ 1, kk, 0); SB(c ^ 1, kk, 1); SB(c ^ 1, kk, 2); }
    RAWBAR; LGKM0;
    __builtin_amdgcn_s_setprio(1); MFMA20(FA0, 0); __builtin_amdgcn_s_setprio(0);
    RAWBAR;
    // P3 (mh1,kh1): all frags resident
    if (st) { SB(c ^ 1, kk, 3); SB(c ^ 1, kk, 4); }
    RAWBAR;
    __builtin_amdgcn_s_setprio(1); MFMA20(FA1, 1); __builtin_amdgcn_s_setprio(0);
    if (st) WAITVM0;    // full drain: publishes ALL waves' staging (no race)
    RAWBAR;
    if (st) { DSB(c ^ 1, 0); DSA(c ^ 1, 0, 0, FA0); }
  }

  // epilogue
#pragma unroll
  for (int m = 0; m < 8; ++m)
#pragma unroll
    for (int n = 0; n < 5; ++n) {
      int gc = tileN + wn * 80 + n * 16 + rl;
      float bv = (gc < 2048) ? bcls[1024 + gc] : bloc[gc - 2048];
#pragma unroll
      for (int r = 0; r < 4; ++r) {
        int gr = tileM + wm * 128 + m * 16 + g4 * 4 + r;
        Yout[(size_t)gr * NY + gc] = f2bf(acc[m][n][r] + bv);
      }
    }
}

// ---------------- out-proj GEMM (r15-style pipelined 128x128 BK=64) + cls GEMV ----
// Blocks 0..255: GEMM out = CTX @ Wout^T + b (rows 0,2048 skipped).
// Blocks 256..767: combine cls partials + GEMV -> out rows 0,2048.
__global__ __launch_bounds__(256)
void gemm_out(const unsigned short* __restrict__ A,     // CTX [4096][1024]
              const unsigned short* __restrict__ B,     // Wout [1024][1024]
              const float* __restrict__ bias0,          // out_b_loc
              float* __restrict__ C,                    // out [4096][1024]
              const float* __restrict__ part,           // cls partials
              const float* __restrict__ Wc,             // out_w_cls
              const float* __restrict__ bc) {           // out_b_cls
  __shared__ unsigned short As2[2][128][64];   // 32 KiB
  __shared__ unsigned short Bs2[2][128][64];   // 32 KiB
  __shared__ float ctx[EE];
  __shared__ float u[HH][8];
  char* ldsA = (char*)As2;
  char* ldsB = (char*)Bs2;

  const int tid = threadIdx.x;

  if (blockIdx.x >= 256) {
    // ===== cls rows: combine 8 chunk-partials then GEMV =====
    const int cid = blockIdx.x - 256;        // 0..511
    const int b = cid >> 8;
    const float* pb = part + (size_t)b * HH * 8 * 66;
    if (tid < HH) {
      const float* pp = pb + tid * 8 * 66;
      float M = -1e30f;
#pragma unroll
      for (int i = 0; i < 8; ++i) M = fmaxf(M, pp[i * 66]);
      float Z = 0.0f, w[8];
#pragma unroll
      for (int i = 0; i < 8; ++i) { w[i] = __expf(pp[i * 66] - M); Z += w[i] * pp[i * 66 + 1]; }
#pragma unroll
      for (int i = 0; i < 8; ++i) u[tid][i] = w[i] / Z;
    }
    __syncthreads();
    for (int k = tid; k < EE; k += 256) {
      int hh = k >> 6, d = k & 63;
      const float* pp = pb + hh * 8 * 66 + 2 + d;
      float a = 0.0f;
#pragma unroll
      for (int i = 0; i < 8; ++i) a += u[hh][i] * pp[i * 66];
      ctx[k] = a;
    }
    __syncthreads();
    int n = (cid & 255) * 4 + (tid >> 6);
    int lane = tid & 63;
    const float* w = Wc + (size_t)n * EE;
    float s = 0.0f;
    for (int k = lane; k < EE; k += 64) s += ctx[k] * w[k];
    for (int o = 32; o; o >>= 1) s += __shfl_xor(s, o);
    if (lane == 0) C[(size_t)b * SS * EE + n] = s + bc[n];
    return;
  }

  // ===== pipelined 128x128 GEMM: 4 waves (2Mx2N), per-wave 64x64, BK=64 =====
  const int wid = tid >> 6;
  const int lane = tid & 63;
  int bid = blockIdx.x;
  bid = (bid & 7) * 32 + (bid >> 3);       // XCD swizzle over 256
  const int tileM = (bid % 32) * 128;
  const int tileN = (bid / 32) * 128;

  const int wm = wid >> 1;     // 0..1 -> 64-row slice
  const int wn = wid & 1;      // 0..1 -> 64-col slice
  const int rl = lane & 15;
  const int g4 = lane >> 4;

  f32x4 acc[4][4] = {};
  short8 FA0[4], FA1[4], FB0[4], FB1[4];

  auto SA2 = [&](int c, int kk, int i) {   // A slab i = rows i*32..i*32+31 (4 KB)
    int flat = i * 4096 + tid * 16;
    int row = flat >> 7;
    int colb = (flat & 127) ^ ((row & 7) << 4);
    gload_lds16(A + (size_t)(tileM + row) * EE + kk + (colb >> 1),
                ldsA + c * 16384 + i * 4096 + wid * 1024);
  };
  auto SB2 = [&](int c, int kk, int i) {
    int flat = i * 4096 + tid * 16;
    int row = flat >> 7;
    int colb = (flat & 127) ^ ((row & 7) << 4);
    gload_lds16(B + (size_t)(tileN + row) * EE + kk + (colb >> 1),
                ldsB + c * 16384 + i * 4096 + wid * 1024);
  };
  auto RDA = [&](int c, int kh, short8* dst) {
#pragma unroll
    for (int m = 0; m < 4; ++m) {
      int row = wm * 64 + m * 16 + rl;
      const char* base = ldsA + c * 16384 + row * 128;
      dst[m] = *(const short8*)(base + ((kh * 64 + g4 * 16) ^ ((row & 7) << 4)));
    }
  };
  auto RDB = [&](int c, int kh, short8* dst) {
#pragma unroll
    for (int n = 0; n < 4; ++n) {
      int row = wn * 64 + n * 16 + rl;
      const char* base = ldsB + c * 16384 + row * 128;
      dst[n] = *(const short8*)(base + ((kh * 64 + g4 * 16) ^ ((row & 7) << 4)));
    }
  };
  auto MF16 = [&](short8* fa, short8* fb) {
    __builtin_amdgcn_s_setprio(1);
#pragma unroll
    for (int m = 0; m < 4; ++m)
#pragma unroll
      for (int n = 0; n < 4; ++n)
        acc[m][n] = __builtin_amdgcn_mfma_f32_16x16x32_bf16(
            fa[m], fb[n], acc[m][n], 0, 0, 0);
    __builtin_amdgcn_s_setprio(0);
  };

  // prologue: stage tile 0 -> buf0, pre-read P0 frags (8 reads)
  SA2(0, 0, 0); SA2(0, 0, 1); SA2(0, 0, 2); SA2(0, 0, 3);
  SB2(0, 0, 0); SB2(0, 0, 1); SB2(0, 0, 2); SB2(0, 0, 3);
  WAITVM0;
  RAWBAR;
  RDA(0, 0, FA0); RDB(0, 0, FB0);

#pragma unroll 1
  for (int t = 0; t < 16; ++t) {
    const int c = t & 1;
    const int kk = (t + 1) * 64;
    const bool st = (t < 15);
    // P0 (kh0): pre-read P1's frags; stage next tile's A
    RDA(c, 1, FA1); RDB(c, 1, FB1);
    if (st) { SA2(c ^ 1, kk, 0); SA2(c ^ 1, kk, 1); SA2(c ^ 1, kk, 2); SA2(c ^ 1, kk, 3); }
    RAWBAR; LGKMW(8);   // waits the 8 pre-seam reads; P1's 8 stay in flight
    MF16(FA0, FB0);
    RAWBAR;
    // P1 (kh1): stage next tile's B
    if (st) { SB2(c ^ 1, kk, 0); SB2(c ^ 1, kk, 1); SB2(c ^ 1, kk, 2); SB2(c ^ 1, kk, 3); }
    RAWBAR; LGKM0;
    MF16(FA1, FB1);
    if (st) WAITVM0;    // full drain: publishes ALL waves' staging (no race)
    RAWBAR;
    if (st) { RDA(c ^ 1, 0, FA0); RDB(c ^ 1, 0, FB0); }
  }

  // epilogue: C row = tileM + wm*64 + m*16 + g4*4 + r, col = tileN + wn*64 + n*16 + rl
#pragma unroll
  for (int m = 0; m < 4; ++m)
#pragma unroll
    for (int n = 0; n < 4; ++n) {
      int gc = tileN + wn * 64 + n * 16 + rl;
      float bv = bias0[gc];
#pragma unroll
      for (int r = 0; r < 4; ++r) {
        int gr = tileM + wm * 64 + m * 16 + g4 * 4 + r;
        if (gr & 2047)   // rows 0 and 2048 belong to the cls blocks
          C[(size_t)gr * EE + gc] = acc[m][n][r] + bv;
      }
    }
}

// ---------------- fused attention: local (x<16) + global partials (x>=16) ----------------
#define QBL 128
#define VT_PAD 168
#define P_PAD 72
__global__ __launch_bounds__(256, 2)
void attn_fused(const float* __restrict__ qcls,
                const unsigned short* __restrict__ Y,
                float* __restrict__ part,
                unsigned short* __restrict__ CTX) {
  const int h = blockIdx.y, b = blockIdx.z;
  const int tid = threadIdx.x, wid = tid >> 6, lane = tid & 63;

  __shared__ unsigned short Vt[64][VT_PAD];
  __shared__ unsigned short Pl[4][32][P_PAD];
  __shared__ float qf[64];
  __shared__ float ps[256];
  __shared__ float red[8];
  __shared__ float pacc[4][64];

  if (blockIdx.x >= 16) {
    // ===== global (cls) attention partial, key-chunk kc =====
    const int kc = blockIdx.x - 16;
    if (tid < 64) qf[tid] = qcls[b * EE + h * DD + tid];
    __syncthreads();

    const int sl = tid >> 3, oct = tid & 7;
    float d8[8];
#pragma unroll
    for (int it = 0; it < 8; ++it) {
      int key = sl + it * 32;
      short8 kv = *(const short8*)&Y[(size_t)(b * SS + kc * 256 + key) * NY + h * DD + oct * 8];
      float d = 0.0f;
#pragma unroll
      for (int e = 0; e < 8; ++e) d += qf[oct * 8 + e] * bf2f((unsigned short)kv[e]);
      d8[it] = d;
    }
#pragma unroll
    for (int it = 0; it < 8; ++it) {
      d8[it] += __shfl_xor(d8[it], 1);
      d8[it] += __shfl_xor(d8[it], 2);
      d8[it] += __shfl_xor(d8[it], 4);
    }
    if (oct == 0) {
#pragma unroll
      for (int it = 0; it < 8; ++it) ps[sl + it * 32] = d8[it] * 0.125f;
    }
    __syncthreads();

    float dot = ps[tid];
    float mx = dot;
    for (int o = 32; o; o >>= 1) mx = fmaxf(mx, __shfl_xor(mx, o));
    if ((tid & 63) == 0) red[tid >> 6] = mx;
    __syncthreads();
    float M = fmaxf(fmaxf(red[0], red[1]), fmaxf(red[2], red[3]));

    float p = __expf(dot - M);
    ps[tid] = p;
    float l = p;
    for (int o = 32; o; o >>= 1) l += __shfl_xor(l, o);
    if ((tid & 63) == 0) red[4 + (tid >> 6)] = l;
    __syncthreads();
    float L = red[4] + red[5] + red[6] + red[7];

    float a8[8] = {0.f, 0.f, 0.f, 0.f, 0.f, 0.f, 0.f, 0.f};
#pragma unroll
    for (int it = 0; it < 8; ++it) {
      int slv = (tid >> 3) + it * 32;
      float p2 = ps[slv];
      short8 v = *(const short8*)&Y[(size_t)(b * SS + kc * 256 + slv) * NY + 1024 + h * DD + oct * 8];
#pragma unroll
      for (int e = 0; e < 8; ++e) a8[e] += p2 * bf2f((unsigned short)v[e]);
    }
#pragma unroll
    for (int e = 0; e < 8; ++e) {
      a8[e] += __shfl_xor(a8[e], 8);
      a8[e] += __shfl_xor(a8[e], 16);
      a8[e] += __shfl_xor(a8[e], 32);
    }
    if (lane < 8) {
#pragma unroll
      for (int e = 0; e < 8; ++e) pacc[wid][lane * 8 + e] = a8[e];
    }
    __syncthreads();
    if (tid < 64) {
      float a = pacc[0][tid] + pacc[1][tid] + pacc[2][tid] + pacc[3][tid];
      float* pp = part + ((size_t)(b * HH + h) * 8 + kc) * 66;
      if (tid == 0) { pp[0] = M; pp[1] = L; }
      pp[2 + tid] = a;
    }
    return;
  }

  // ===== local attention via MFMA =====
  const int s0 = blockIdx.x * QBL;
  const int rl = lane & 15, g = lane >> 4;

  for (int task = tid; task < 1280; task += 256) {
    int row = task >> 3, oc = task & 7;
    int kg = min(max(s0 - 16 + row, 0), SS - 1);
    short8 v = *(const short8*)&Y[(size_t)(b * SS + kg) * NY + 4096 + h * DD + oc * 8];
#pragma unroll
    for (int e = 0; e < 8; ++e) Vt[oc * 8 + e][row] = (unsigned short)v[e];
  }
  __syncthreads();

  const int qb = s0 + wid * 32;
  const int kb = qb - 16;

  short8 ak[4][2];
#pragma unroll
  for (int kt = 0; kt < 4; ++kt) {
    int kg = min(max(kb + kt * 16 + rl, 0), SS - 1);
    const unsigned short* kr = &Y[(size_t)(b * SS + kg) * NY + 3072 + h * DD + g * 8];
#pragma unroll
    for (int ks = 0; ks < 2; ++ks) ak[kt][ks] = *(const short8*)(kr + ks * 32);
  }
  short8 bq[2][2];
#pragma unroll
  for (int cc = 0; cc < 2; ++cc) {
    const unsigned short* qr = &Y[(size_t)(b * SS + qb + cc * 16 + rl) * NY + 2048 + h * DD + g * 8];
#pragma unroll
    for (int ks = 0; ks < 2; ++ks) bq[cc][ks] = *(const short8*)(qr + ks * 32);
  }

  f32x4 accs[4][2] = {};
#pragma unroll
  for (int kt = 0; kt < 4; ++kt)
#pragma unroll
    for (int cc = 0; cc < 2; ++cc)
#pragma unroll
      for (int ks = 0; ks < 2; ++ks)
        accs[kt][cc] = __builtin_amdgcn_mfma_f32_16x16x32_bf16(
            ak[kt][ks], bq[cc][ks], accs[kt][cc], 0, 0, 0);

  float mrow[2] = {-3e38f, -3e38f};
#pragma unroll
  for (int kt = 0; kt < 4; ++kt)
#pragma unroll
    for (int cc = 0; cc < 2; ++cc)
#pragma unroll
      for (int r = 0; r < 4; ++r) {
        int kg = kb + kt * 16 + 4 * g + r;
        int qg = qb + cc * 16 + rl;
        bool valid = (kg >= qg - 16) && (kg <= qg + 16) && (kg >= 1) && (kg < SS);
        float v = valid ? accs[kt][cc][r] : -3e38f;
        accs[kt][cc][r] = v;
        mrow[cc] = fmaxf(mrow[cc], v);
      }
#pragma unroll
  for (int cc = 0; cc < 2; ++cc) {
    float m = mrow[cc];
    m = fmaxf(m, __shfl_xor(m, 16));
    m = fmaxf(m, __shfl_xor(m, 32));
    mrow[cc] = m;
  }

  float zrow[2] = {0.0f, 0.0f};
#pragma unroll
  for (int cc = 0; cc < 2; ++cc)
#pragma unroll
    for (int kt = 0; kt < 4; ++kt) {
      ushort4 pw;
#pragma unroll
      for (int r = 0; r < 4; ++r) {
        float p = __expf((accs[kt][cc][r] - mrow[cc]) * 0.125f);
        zrow[cc] += p;
        ((unsigned short*)&pw)[r] = f2bf(p);
      }
      *(ushort4*)&Pl[wid][cc * 16 + rl][kt * 16 + 4 * g] = pw;
    }
#pragma unroll
  for (int cc = 0; cc < 2; ++cc) {
    float z = zrow[cc];
    z += __shfl_xor(z, 16);
    z += __shfl_xor(z, 32);
    zrow[cc] = 1.0f / z;
  }

  f32x4 accp[4][2] = {};
#pragma unroll
  for (int ks = 0; ks < 2; ++ks) {
    short8 bp[2];
#pragma unroll
    for (int cc = 0; cc < 2; ++cc)
      bp[cc] = *(const short8*)&Pl[wid][cc * 16 + rl][ks * 32 + g * 8];
#pragma unroll
    for (int mt = 0; mt < 4; ++mt) {
      short8 av = *(const short8*)&Vt[mt * 16 + rl][wid * 32 + ks * 32 + g * 8];
#pragma unroll
      for (int cc = 0; cc < 2; ++cc)
        accp[mt][cc] = __builtin_amdgcn_mfma_f32_16x16x32_bf16(
            av, bp[cc], accp[mt][cc], 0, 0, 0);
    }
  }

#pragma unroll
  for (int mt = 0; mt < 4; ++mt)
#pragma unroll
    for (int cc = 0; cc < 2; ++cc) {
      int token = qb + cc * 16 + rl;
      if (token == 0) {
        *(ushort4*)&CTX[(size_t)(b * SS) * EE + h * DD + mt * 16 + 4 * g] = ushort4{0, 0, 0, 0};
        continue;
      }
      ushort4 o;
#pragma unroll
      for (int r = 0; r < 4; ++r)
        ((unsigned short*)&o)[r] = f2bf(accp[mt][cc][r] * zrow[cc]);
      *(ushort4*)&CTX[(size_t)(b * SS + token) * EE + h * DD + mt * 16 + 4 * g] = o;
    }
}

extern "C" void kernel_launch(void* const* d_in, const int* in_sizes, int n_in,
                              void* d_out, int out_size, void* d_ws, size_t ws_size,
                              hipStream_t stream) {
  const float* hs        = (const float*)d_in[0];
  const float* in_w_cls  = (const float*)d_in[1];
  const float* in_b_cls  = (const float*)d_in[2];
  const float* out_w_cls = (const float*)d_in[3];
  const float* out_b_cls = (const float*)d_in[4];
  const float* in_w_loc  = (const float*)d_in[5];
  const float* in_b_loc  = (const float*)d_in[6];
  const float* out_w_loc = (const float*)d_in[7];
  const float* out_b_loc = (const float*)d_in[8];
  float* out = (float*)d_out;

  const int M = BB * SS;  // 4096
  char* ws = (char*)d_ws;
  size_t off = 0;
  auto alloc = [&](size_t bytes) { char* p = ws + off; off += (bytes + 255) & ~(size_t)255; return p; };
  unsigned short* Xbf  = (unsigned short*)alloc((size_t)M * EE * 2);
  unsigned short* W    = (unsigned short*)alloc((size_t)NY * EE * 2);
  unsigned short* Wout = (unsigned short*)alloc((size_t)EE * EE * 2);
  unsigned short* Yb   = (unsigned short*)alloc((size_t)M * NY * 2);
  unsigned short* CTX  = (unsigned short*)alloc((size_t)M * EE * 2);
  float* qcls = (float*)alloc(2 * EE * 4);
  float* part = (float*)alloc((size_t)BB * HH * 8 * 66 * 4);

  // 1) fused casts + q_cls GEMV
  cast_all<<<10752, 256, 0, stream>>>(
      hs, Xbf,
      in_w_cls + (size_t)EE * EE, W,
      in_w_loc, W + (size_t)2048 * EE,
      out_w_loc, Wout,
      in_w_cls, in_b_cls, qcls);

  // 2) merged projection GEMM (r15-proven A-frag pipelined, 256x320, 256 blocks)
  gemm8p<<<256, 512, 0, stream>>>(Xbf, W, in_b_cls, in_b_loc, Yb);

  // 3) fused attention (coalesced QK dot + Vt staging + V-accumulate)
  attn_fused<<<dim3(24, HH, BB), 256, 0, stream>>>(qcls, Yb, part, CTX);

  // 4) out-proj GEMM (pipelined BK=64) + cls rows (one launch)
  gemm_out<<<768, 256, 0, stream>>>(CTX, Wout, out_b_loc, out,
                                    part, out_w_cls, out_b_cls);
}